// Round 19
// baseline (275.718 us; speedup 1.0000x reference)
//
#include <hip/hip_runtime.h>
#include <hip/hip_bf16.h>
#include <math.h>

#define L_SEQ  2048
#define BATCH  2
#define DMODEL 1024
#define DINNER 2048
#define DSTATE 16
#define NCHUNK 64
#define LCH    (L_SEQ / NCHUNK)  // 32

typedef __attribute__((ext_vector_type(8))) short bf16x8;
typedef __attribute__((ext_vector_type(4))) float f32x4;

__device__ __forceinline__ unsigned short f2bu(float x) {
    __hip_bfloat16 h = __float2bfloat16(x);
    return __builtin_bit_cast(unsigned short, h);
}
__device__ __forceinline__ float bu2f(unsigned short u) {
    __hip_bfloat16 h = __builtin_bit_cast(__hip_bfloat16, u);
    return __bfloat162float(h);
}
// v_exp_f32: D = 2^S0 (hardware exp2)
__device__ __forceinline__ float fast_exp2(float x) {
    float r; asm("v_exp_f32 %0, %1" : "=v"(r) : "v"(x)); return r;
}
#define LOG2E 1.44269504088896f

// ---------------------------------------------------------------------------
// Fused fp32 -> bf16 conversion for all static operands (one launch).
// ---------------------------------------------------------------------------
__global__ __launch_bounds__(256) void cvt_all(
    const float* __restrict__ Wout, const float* __restrict__ Win,
    const float* __restrict__ xh,   const float* __restrict__ Whf,
    const float* __restrict__ Wx,   const float* __restrict__ Wdt,
    __hip_bfloat16* __restrict__ dWout, __hip_bfloat16* __restrict__ dWin,
    __hip_bfloat16* __restrict__ dxh,   __hip_bfloat16* __restrict__ dWhf,
    __hip_bfloat16* __restrict__ dWx,   __hip_bfloat16* __restrict__ dWdt)
{
    int bid = blockIdx.x;
    const float* s; __hip_bfloat16* d;
    if (bid < 2048)       { s = Wout; d = dWout; }
    else if (bid < 6144)  { s = Win;  d = dWin;  bid -= 2048; }
    else if (bid < 10240) { s = xh;   d = dxh;   bid -= 6144; }
    else if (bid < 11264) { s = Whf;  d = dWhf;  bid -= 10240; }
    else if (bid < 11520) {
        // W_x (96x2048) -> 128x2048, rows 96..127 zero
        bid -= 11264;
        const int i = (bid * 256 + threadIdx.x) * 4;
        const int r = i >> 11;
        ushort4 u = {0, 0, 0, 0};
        if (r < 96) {
            const float4 v = *reinterpret_cast<const float4*>(&Wx[i]);
            u.x = f2bu(v.x); u.y = f2bu(v.y); u.z = f2bu(v.z); u.w = f2bu(v.w);
        }
        *reinterpret_cast<ushort4*>(&dWx[i]) = u;
        return;
    }
    else                  { s = Wdt;  d = dWdt;  bid -= 11520; }
    const int i = (bid * 256 + threadIdx.x) * 4;
    const float4 v = *reinterpret_cast<const float4*>(&s[i]);
    ushort4 u;
    u.x = f2bu(v.x); u.y = f2bu(v.y); u.z = f2bu(v.z); u.w = f2bu(v.w);
    *reinterpret_cast<ushort4*>(&d[i]) = u;
}

// ---------------------------------------------------------------------------
// 256x256-tile MFMA bf16 GEMM (T2-swizzled, conflict-free; R16-verified).
// 8 waves (2Mx4N), template KB = K-step depth:
//   KB=64: 128KB LDS, 64 MFMA/wave/step (G2 config, bit-identical to R18).
//   KB=32: 64KB LDS -> 2 blocks/CU co-resident (inter-block latency overlap,
//          the m114 mechanism) for split-K G7. Swizzle key adapts: KB=64 ->
//          r&7 (8 chunks/row); KB=32 -> (r>>1)&3 (4 chunks/row, row stride
//          64B=16 banks: fr parity supplies bit4, key must cycle 4 values
//          across same-parity lanes -> 2-way bank access, free).
// Both sides of the swizzle use the same involution (rule 21).
// EPI 2: bf16 split planes (col<2048 -> Cb=x_in else Cb2=z), G2.
// EPI 4: bf16 split-K partials: Cb + z*(rows*ncols), G7.
// ---------------------------------------------------------------------------
template <int EPI, int KB>
__global__ __launch_bounds__(512) void mfma_gemm256(
    const __hip_bfloat16* __restrict__ A, int lda,
    const __hip_bfloat16* __restrict__ Bw, int ldb,
    int ksz,
    __hip_bfloat16* __restrict__ Cb,
    __hip_bfloat16* __restrict__ Cb2)
{
    constexpr int CH = KB / 8;     // 16B chunks per row
    constexpr int NL = KB / 16;    // staging issues per operand
    __shared__ unsigned short As[2][256 * KB];
    __shared__ unsigned short Bs[2][256 * KB];
    const int tid = threadIdx.x;
    const int row0 = blockIdx.y * 256;
    const int col0 = blockIdx.x * 256;
    const int wid = tid >> 6, lane = tid & 63;
    const int wr = wid >> 2, wc = wid & 3;
    const int fr = lane & 15, fq = lane >> 4;
    const int kz0 = blockIdx.z * ksz;
    const int nk = ksz / KB;

    f32x4 acc[8][4];
#pragma unroll
    for (int m = 0; m < 8; m++)
#pragma unroll
        for (int n = 0; n < 4; n++) acc[m][n] = (f32x4){0.f, 0.f, 0.f, 0.f};

    // staging: 256*CH 16B-items per operand; item -> LDS row r, chunk sl
    // (linear dest). SOURCE chunk = sl ^ key(r)   [T2 swizzle].
    size_t gA[NL], gB[NL];
    int ld0[NL];
#pragma unroll
    for (int l = 0; l < NL; l++) {
        const int item = l * 512 + tid;
        const int r = item / CH, sl = item & (CH - 1);
        const int key = (KB == 64) ? (r & 7) : ((r >> 1) & 3);
        const int slw = sl ^ key;
        gA[l] = (size_t)(row0 + r) * lda + slw * 8;
        gB[l] = (size_t)(col0 + r) * ldb + slw * 8;
        ld0[l] = item * 8;
    }

#if __has_builtin(__builtin_amdgcn_global_load_lds)
    auto STAGE = [&](int buf, int koff) {
#pragma unroll
        for (int l = 0; l < NL; l++)
            __builtin_amdgcn_global_load_lds(
                (const __attribute__((address_space(1))) unsigned int*)(A + gA[l] + koff),
                (__attribute__((address_space(3))) unsigned int*)&As[buf][ld0[l]], 16, 0, 0);
#pragma unroll
        for (int l = 0; l < NL; l++)
            __builtin_amdgcn_global_load_lds(
                (const __attribute__((address_space(1))) unsigned int*)(Bw + gB[l] + koff),
                (__attribute__((address_space(3))) unsigned int*)&Bs[buf][ld0[l]], 16, 0, 0);
    };
#else
    auto STAGE = [&](int buf, int koff) {
#pragma unroll
        for (int l = 0; l < NL; l++) {
            *reinterpret_cast<uint4*>(&As[buf][ld0[l]]) =
                *reinterpret_cast<const uint4*>(A + gA[l] + koff);
            *reinterpret_cast<uint4*>(&Bs[buf][ld0[l]]) =
                *reinterpret_cast<const uint4*>(Bw + gB[l] + koff);
        }
    };
#endif

    STAGE(0, kz0);
    __syncthreads();
    int buf = 0;
    const int rkey = (KB == 64) ? (fr & 7) : ((fr >> 1) & 3);
    for (int t = 0; t < nk; t++) {
        if (t + 1 < nk) STAGE(buf ^ 1, kz0 + (t + 1) * KB);
#pragma unroll
        for (int ks = 0; ks < KB / 32; ks++) {
            bf16x8 a[8], b[4];
#pragma unroll
            for (int m = 0; m < 8; m++)
                a[m] = *reinterpret_cast<const bf16x8*>(
                    &As[buf][(wr * 128 + m * 16 + fr) * KB +
                             (((ks * 4 + fq) ^ rkey) * 8)]);
#pragma unroll
            for (int n = 0; n < 4; n++)
                b[n] = *reinterpret_cast<const bf16x8*>(
                    &Bs[buf][(wc * 64 + n * 16 + fr) * KB +
                             (((ks * 4 + fq) ^ rkey) * 8)]);
            __builtin_amdgcn_s_setprio(1);     // T5
#pragma unroll
            for (int m = 0; m < 8; m++)
#pragma unroll
                for (int n = 0; n < 4; n++)
                    acc[m][n] = __builtin_amdgcn_mfma_f32_16x16x32_bf16(
                        a[m], b[n], acc[m][n], 0, 0, 0);
            __builtin_amdgcn_s_setprio(0);
        }
        __syncthreads();
        buf ^= 1;
    }

    // C/D layout: col = lane&15, row = (lane>>4)*4 + reg
    const int r0 = row0 + wr * 128;
    const int c0 = col0 + wc * 64;
    const bool isx = (col0 < 2048);
    const int ncols = gridDim.x * 256;
    __hip_bfloat16* pz = Cb +
        (size_t)blockIdx.z * (size_t)(gridDim.y * 256) * ncols;
#pragma unroll
    for (int m = 0; m < 8; m++)
#pragma unroll
        for (int n = 0; n < 4; n++) {
            const int col = c0 + n * 16 + fr;
#pragma unroll
            for (int j = 0; j < 4; j++) {
                const int row = r0 + m * 16 + fq * 4 + j;
                const __hip_bfloat16 v = __float2bfloat16(acc[m][n][j]);
                if (EPI == 2) {
                    if (isx) Cb[(size_t)row * 2048 + col] = v;
                    else     Cb2[(size_t)row * 2048 + col - 2048] = v;
                } else {
                    pz[(size_t)row * ncols + col] = v;
                }
            }
        }
}

// ---------------------------------------------------------------------------
// MFMA bf16 GEMM: 128x128 tile, BK=32, 4 waves, 2-barrier loop.
// SWAP: blockIdx.x = ROW-block (XCD panel pinning for skinny-N G1).
// EPI: 0 fp32 C; 1 bf16 C = sigmoid(acc+bias)*mul; 3 bf16 softplus(acc+bias);
//      5 bf16 split-K partials (Cb + z*rows*ldc).
// ---------------------------------------------------------------------------
template <int EPI, bool SWAP>
__global__ __launch_bounds__(256) void mfma_gemm(
    const __hip_bfloat16* __restrict__ A, int lda,
    const __hip_bfloat16* __restrict__ Bw, int ldb,
    int ksz,
    float* __restrict__ Cf, int ldc,
    __hip_bfloat16* __restrict__ Cb,
    const float* __restrict__ bias,
    const float* __restrict__ mul, int ldmul)
{
    __shared__ unsigned short As[128 * 32];
    __shared__ unsigned short Bs[128 * 32];
    const int tid = threadIdx.x;
    const int by = SWAP ? blockIdx.x : blockIdx.y;   // row-block
    const int bx = SWAP ? blockIdx.y : blockIdx.x;   // col-block
    const int row0 = by * 128;
    const int col0 = bx * 128;
    const int wid = tid >> 6, lane = tid & 63;
    const int wr = wid >> 1, wc = wid & 1;
    const int fr = lane & 15, fq = lane >> 4;
    const int kz0 = blockIdx.z * ksz;

    f32x4 acc[4][4];
#pragma unroll
    for (int i = 0; i < 4; i++)
#pragma unroll
        for (int j = 0; j < 4; j++) acc[i][j] = (f32x4){0.f, 0.f, 0.f, 0.f};

    const int i0 = tid, i1 = tid + 256;
    const size_t ga0 = (size_t)(row0 + (i0 >> 2)) * lda + (i0 & 3) * 8;
    const size_t ga1 = (size_t)(row0 + (i1 >> 2)) * lda + (i1 & 3) * 8;
    const size_t gb0 = (size_t)(col0 + (i0 >> 2)) * ldb + (i0 & 3) * 8;
    const size_t gb1 = (size_t)(col0 + (i1 >> 2)) * ldb + (i1 & 3) * 8;
    const int nk = ksz >> 5;

    for (int kk = 0; kk < nk; kk++) {
        const int koff = kz0 + kk * 32;
#if __has_builtin(__builtin_amdgcn_global_load_lds)
        __syncthreads();   // readers of previous tile done
        __builtin_amdgcn_global_load_lds(
            (const __attribute__((address_space(1))) unsigned int*)(A + ga0 + koff),
            (__attribute__((address_space(3))) unsigned int*)&As[i0 * 8], 16, 0, 0);
        __builtin_amdgcn_global_load_lds(
            (const __attribute__((address_space(1))) unsigned int*)(A + ga1 + koff),
            (__attribute__((address_space(3))) unsigned int*)&As[i1 * 8], 16, 0, 0);
        __builtin_amdgcn_global_load_lds(
            (const __attribute__((address_space(1))) unsigned int*)(Bw + gb0 + koff),
            (__attribute__((address_space(3))) unsigned int*)&Bs[i0 * 8], 16, 0, 0);
        __builtin_amdgcn_global_load_lds(
            (const __attribute__((address_space(1))) unsigned int*)(Bw + gb1 + koff),
            (__attribute__((address_space(3))) unsigned int*)&Bs[i1 * 8], 16, 0, 0);
        __syncthreads();   // staged tile visible (vmcnt drained by barrier)
#else
        const uint4 va0 = *reinterpret_cast<const uint4*>(A + ga0 + koff);
        const uint4 va1 = *reinterpret_cast<const uint4*>(A + ga1 + koff);
        const uint4 vb0 = *reinterpret_cast<const uint4*>(Bw + gb0 + koff);
        const uint4 vb1 = *reinterpret_cast<const uint4*>(Bw + gb1 + koff);
        __syncthreads();
        *reinterpret_cast<uint4*>(&As[i0 * 8]) = va0;
        *reinterpret_cast<uint4*>(&As[i1 * 8]) = va1;
        *reinterpret_cast<uint4*>(&Bs[i0 * 8]) = vb0;
        *reinterpret_cast<uint4*>(&Bs[i1 * 8]) = vb1;
        __syncthreads();
#endif
        bf16x8 af[4], bq[4];
#pragma unroll
        for (int rb = 0; rb < 4; rb++)
            af[rb] = *reinterpret_cast<const bf16x8*>(
                &As[(wr * 64 + rb * 16 + fr) * 32 + fq * 8]);
#pragma unroll
        for (int cb = 0; cb < 4; cb++)
            bq[cb] = *reinterpret_cast<const bf16x8*>(
                &Bs[(wc * 64 + cb * 16 + fr) * 32 + fq * 8]);
#pragma unroll
        for (int rb = 0; rb < 4; rb++)
#pragma unroll
            for (int cb = 0; cb < 4; cb++)
                acc[rb][cb] = __builtin_amdgcn_mfma_f32_16x16x32_bf16(
                    af[rb], bq[cb], acc[rb][cb], 0, 0, 0);
    }

    // C/D layout: col = lane&15, row = (lane>>4)*4 + reg
    const int nrows = (SWAP ? gridDim.x : gridDim.y) * 128;
    float* Cz = Cf + (EPI == 0 ?
        (size_t)blockIdx.z * (size_t)nrows * ldc : 0);
    __hip_bfloat16* Cbz = Cb + (EPI == 5 ?
        (size_t)blockIdx.z * (size_t)nrows * ldc : 0);
    const int r0 = row0 + wr * 64, c0 = col0 + wc * 64;
#pragma unroll
    for (int rb = 0; rb < 4; rb++)
#pragma unroll
        for (int cb = 0; cb < 4; cb++) {
            const int col = c0 + cb * 16 + fr;
#pragma unroll
            for (int j = 0; j < 4; j++) {
                const int row = r0 + rb * 16 + fq * 4 + j;
                float v = acc[rb][cb][j];
                if (EPI == 0) {
                    Cz[(size_t)row * ldc + col] = v;
                } else if (EPI == 1) {
                    v = 1.f / (1.f + __expf(-(v + bias[col])));
                    v *= mul[(size_t)row * ldmul + col];
                    Cb[(size_t)row * ldc + col] = __float2bfloat16(v);
                } else if (EPI == 5) {
                    Cbz[(size_t)row * ldc + col] = __float2bfloat16(v);
                } else {
                    v += bias[col];
                    v = (v > 20.f) ? v : log1pf(__expf(v));
                    Cb[(size_t)row * ldc + col] = __float2bfloat16(v);
                }
            }
        }
}

// Split-K reduce for x_dbl (bf16 partials, 8 slices of 4096x128), emits
// fp32 xdbl + bf16 dt_r.
__global__ __launch_bounds__(256) void reduce_xdbl(
    const __hip_bfloat16* __restrict__ part, float* __restrict__ xdbl,
    __hip_bfloat16* __restrict__ dtr)
{
    const int i = blockIdx.x * 256 + threadIdx.x;   // 4096*128
    float s = 0.f;
#pragma unroll
    for (int j = 0; j < 8; j++)
        s += __bfloat162float(part[(size_t)j * 524288 + i]);
    xdbl[i] = s;
    const int col = i & 127;
    if (col < 64) dtr[((i >> 7) << 6) + col] = __float2bfloat16(s);
}

// G7 split-K=8 reduce: out = sum of 8 bf16 partial slices -> fp32. vec4.
__global__ __launch_bounds__(256) void reduce_out8(
    const __hip_bfloat16* __restrict__ part, float* __restrict__ out)
{
    const int i = (blockIdx.x * 256 + threadIdx.x) * 4;   // 4,194,304 elems
    float s0 = 0.f, s1 = 0.f, s2 = 0.f, s3 = 0.f;
#pragma unroll
    for (int z = 0; z < 8; z++) {
        const ushort4 u = *reinterpret_cast<const ushort4*>(
            &part[(size_t)z * 4194304 + i]);
        s0 += bu2f(u.x); s1 += bu2f(u.y); s2 += bu2f(u.z); s3 += bu2f(u.w);
    }
    *reinterpret_cast<float4*>(&out[i]) = make_float4(s0, s1, s2, s3);
}

// ---------------------------------------------------------------------------
// Depthwise causal conv (width 4) + bias + SiLU, 4 consecutive e per thread.
// ---------------------------------------------------------------------------
__global__ __launch_bounds__(256) void conv_silu_kernel(
    const __hip_bfloat16* __restrict__ xin_b, const float* __restrict__ cw,
    const float* __restrict__ cb, __hip_bfloat16* __restrict__ xcb)
{
    const int bid = blockIdx.x;
    const int row = bid >> 1;
    const int e = ((bid & 1) << 10) + threadIdx.x * 4;
    const int t = row & (L_SEQ - 1);
    float w[16];
    *(float4*)&w[0]  = *(const float4*)&cw[e * 4];
    *(float4*)&w[4]  = *(const float4*)&cw[e * 4 + 4];
    *(float4*)&w[8]  = *(const float4*)&cw[e * 4 + 8];
    *(float4*)&w[12] = *(const float4*)&cw[e * 4 + 12];
    const float4 bias = *(const float4*)&cb[e];
    float s0 = bias.x, s1 = bias.y, s2 = bias.z, s3 = bias.w;
#pragma unroll
    for (int j = 0; j < 4; j++) {
        const int tt = t - 3 + j;
        if (tt >= 0) {
            const ushort4 xv = *(const ushort4*)&xin_b[
                (size_t)(row - 3 + j) * 2048 + e];
            s0 = fmaf(w[j],      bu2f(xv.x), s0);
            s1 = fmaf(w[4 + j],  bu2f(xv.y), s1);
            s2 = fmaf(w[8 + j],  bu2f(xv.z), s2);
            s3 = fmaf(w[12 + j], bu2f(xv.w), s3);
        }
    }
    ushort4 o;
    o.x = f2bu(s0 / (1.f + __expf(-s0)));
    o.y = f2bu(s1 / (1.f + __expf(-s1)));
    o.z = f2bu(s2 / (1.f + __expf(-s2)));
    o.w = f2bu(s3 / (1.f + __expf(-s3)));
    *(ushort4*)&xcb[(size_t)row * 2048 + e] = o;
}

// ---------------------------------------------------------------------------
// Chunked selective scan, lane-owns-channel layout. NCHUNK=64, LCH=32.
// ---------------------------------------------------------------------------
__global__ __launch_bounds__(256) void scan_pass_a(
    const __hip_bfloat16* __restrict__ dtb, const __hip_bfloat16* __restrict__ xcb,
    const float* __restrict__ xdbl, const float* __restrict__ A_log,
    __hip_bfloat16* __restrict__ hloc, __hip_bfloat16* __restrict__ Pp)
{
    __shared__ float sB[LCH][16];
    const int tid = threadIdx.x;
    const int e = (blockIdx.x << 8) + tid;
    const int chunk = blockIdx.y;             // 0..NCHUNK-2
    const int b = blockIdx.z;
    const int t0 = chunk * LCH;

    if (tid < LCH * 4) {
        const int r = tid >> 2, sl = tid & 3;
        *(float4*)&sB[r][sl * 4] =
            *(const float4*)&xdbl[(size_t)(b * L_SEQ + t0 + r) * 128 + 64 + sl * 4];
    }
    float av[16];
#pragma unroll
    for (int sq = 0; sq < 4; sq++) {
        const float4 al = *(const float4*)&A_log[e * 16 + sq * 4];
#pragma unroll
        for (int j = 0; j < 4; j++)
            av[sq * 4 + j] = -fast_exp2(((const float*)&al)[j] * LOG2E);
    }
    float h[16];
#pragma unroll
    for (int s = 0; s < 16; s++) h[s] = 0.f;
    float sdt = 0.f;
    __syncthreads();

    const size_t rb = (size_t)(b * L_SEQ + t0) * 2048 + e;
    float dtv_n = __bfloat162float(dtb[rb]);
    float xv_n = __bfloat162float(xcb[rb]);
    for (int t = 0; t < LCH; t++) {
        const float dtv = dtv_n, xv = xv_n;
        if (t + 1 < LCH) {
            dtv_n = __bfloat162float(dtb[rb + (size_t)(t + 1) * 2048]);
            xv_n = __bfloat162float(xcb[rb + (size_t)(t + 1) * 2048]);
        }
        sdt += dtv;
        const float dtx = dtv * xv;
        const float dl2 = dtv * LOG2E;
#pragma unroll
        for (int sq = 0; sq < 4; sq++) {
            const float4 B4 = *(const float4*)&sB[t][sq * 4];
#pragma unroll
            for (int j = 0; j < 4; j++) {
                const int s = sq * 4 + j;
                const float Bv = ((const float*)&B4)[j];
                h[s] = fmaf(fast_exp2(dl2 * av[s]), h[s], Bv * dtx);
            }
        }
    }
    const size_t o = (((size_t)chunk * BATCH + b) * 2048 + e) * 16;
#pragma unroll
    for (int sq = 0; sq < 4; sq++) {
        ushort4 uh, up;
        uh.x = f2bu(h[sq * 4]);     uh.y = f2bu(h[sq * 4 + 1]);
        uh.z = f2bu(h[sq * 4 + 2]); uh.w = f2bu(h[sq * 4 + 3]);
        up.x = f2bu(fast_exp2(av[sq * 4] * sdt * LOG2E));
        up.y = f2bu(fast_exp2(av[sq * 4 + 1] * sdt * LOG2E));
        up.z = f2bu(fast_exp2(av[sq * 4 + 2] * sdt * LOG2E));
        up.w = f2bu(fast_exp2(av[sq * 4 + 3] * sdt * LOG2E));
        *(ushort4*)&hloc[o + sq * 4] = uh;
        *(ushort4*)&Pp[o + sq * 4] = up;
    }
}

__global__ __launch_bounds__(256) void scan_pass_b(
    const __hip_bfloat16* __restrict__ hloc, const __hip_bfloat16* __restrict__ Pp,
    __hip_bfloat16* __restrict__ h0)
{
    const int idx = blockIdx.x * 256 + threadIdx.x;   // 65536
    float h = 0.f;
    h0[idx] = __float2bfloat16(0.f);
    for (int c = 0; c < NCHUNK - 1; c++) {
        const float P = __bfloat162float(Pp[(size_t)c * 65536 + idx]);
        const float hl = __bfloat162float(hloc[(size_t)c * 65536 + idx]);
        h = fmaf(P, h, hl);
        h0[(size_t)(c + 1) * 65536 + idx] = __float2bfloat16(h);
    }
}

__global__ __launch_bounds__(256) void scan_pass_c(
    const __hip_bfloat16* __restrict__ dtb, const __hip_bfloat16* __restrict__ xcb,
    const float* __restrict__ xdbl, const __hip_bfloat16* __restrict__ zb,
    const float* __restrict__ A_log, const float* __restrict__ Dw,
    const __hip_bfloat16* __restrict__ h0, __hip_bfloat16* __restrict__ yb)
{
    __shared__ float sB[LCH][16];
    __shared__ float sC[LCH][16];
    const int tid = threadIdx.x;
    const int e = (blockIdx.x << 8) + tid;
    const int chunk = blockIdx.y;
    const int b = blockIdx.z;
    const int t0 = chunk * LCH;

    if (tid < LCH * 4) {
        const int r = tid >> 2, sl = tid & 3;
        *(float4*)&sB[r][sl * 4] =
            *(const float4*)&xdbl[(size_t)(b * L_SEQ + t0 + r) * 128 + 64 + sl * 4];
    } else if (tid < LCH * 8) {
        const int t2 = tid - LCH * 4;
        const int r = t2 >> 2, sl = t2 & 3;
        *(float4*)&sC[r][sl * 4] =
            *(const float4*)&xdbl[(size_t)(b * L_SEQ + t0 + r) * 128 + 80 + sl * 4];
    }
    float av[16];
#pragma unroll
    for (int sq = 0; sq < 4; sq++) {
        const float4 al = *(const float4*)&A_log[e * 16 + sq * 4];
#pragma unroll
        for (int j = 0; j < 4; j++)
            av[sq * 4 + j] = -fast_exp2(((const float*)&al)[j] * LOG2E);
    }
    const float De = Dw[e];
    float h[16];
    const size_t o = (((size_t)chunk * BATCH + b) * 2048 + e) * 16;
#pragma unroll
    for (int sq = 0; sq < 4; sq++) {
        const ushort4 hv = *(const ushort4*)&h0[o + sq * 4];
        h[sq * 4]     = bu2f(hv.x); h[sq * 4 + 1] = bu2f(hv.y);
        h[sq * 4 + 2] = bu2f(hv.z); h[sq * 4 + 3] = bu2f(hv.w);
    }
    __syncthreads();

    const size_t rb = (size_t)(b * L_SEQ + t0) * 2048 + e;
    float dtv_n = __bfloat162float(dtb[rb]);
    float xv_n = __bfloat162float(xcb[rb]);
    float zv_n = __bfloat162float(zb[rb]);
    for (int t = 0; t < LCH; t++) {
        const float dtv = dtv_n, xv = xv_n, zv = zv_n;
        if (t + 1 < LCH) {
            dtv_n = __bfloat162float(dtb[rb + (size_t)(t + 1) * 2048]);
            xv_n = __bfloat162float(xcb[rb + (size_t)(t + 1) * 2048]);
            zv_n = __bfloat162float(zb[rb + (size_t)(t + 1) * 2048]);
        }
        const float dtx = dtv * xv;
        const float dl2 = dtv * LOG2E;
        float yp0 = 0.f, yp1 = 0.f, yp2 = 0.f, yp3 = 0.f;
#pragma unroll
        for (int sq = 0; sq < 4; sq++) {
            const float4 B4 = *(const float4*)&sB[t][sq * 4];
            const float4 C4 = *(const float4*)&sC[t][sq * 4];
#pragma unroll
            for (int j = 0; j < 4; j++) {
                const int s = sq * 4 + j;
                const float Bv = ((const float*)&B4)[j];
                const float Cv = ((const float*)&C4)[j];
                h[s] = fmaf(fast_exp2(dl2 * av[s]), h[s], Bv * dtx);
                if (sq == 0) yp0 = fmaf(h[s], Cv, yp0);
                else if (sq == 1) yp1 = fmaf(h[s], Cv, yp1);
                else if (sq == 2) yp2 = fmaf(h[s], Cv, yp2);
                else yp3 = fmaf(h[s], Cv, yp3);
            }
        }
        float yv = (yp0 + yp1) + (yp2 + yp3);
        yv = fmaf(De, xv, yv);
        const float sig = 1.f / (1.f + __expf(-zv));
        yb[rb + (size_t)t * 2048] = __float2bfloat16(yv * zv * sig);
    }
}

extern "C" void kernel_launch(void* const* d_in, const int* in_sizes, int n_in,
                              void* d_out, int out_size, void* d_ws, size_t ws_size,
                              hipStream_t stream)
{
    const float* x_f    = (const float*)d_in[0];
    const float* x_h    = (const float*)d_in[1];
    const float* W_hf   = (const float*)d_in[2];
    const float* b_hf   = (const float*)d_in[3];
    const float* W_in   = (const float*)d_in[4];
    const float* conv_w = (const float*)d_in[5];
    const float* conv_b = (const float*)d_in[6];
    const float* W_x    = (const float*)d_in[7];
    const float* W_dt   = (const float*)d_in[8];
    const float* b_dt   = (const float*)d_in[9];
    const float* A_log  = (const float*)d_in[10];
    const float* Dw     = (const float*)d_in[11];
    const float* W_out  = (const float*)d_in[12];
    float* out = (float*)d_out;
    float* ws  = (float*)d_ws;

    // Workspace (f32 units; total 35,979,264 f = 143.9 MB, proven-safe).
    // G7 split-K=8 bf16 partials: 8 x 4,194,304 bf16 = 16,777,216 f at
    // ws+10813440 (xin_b..dt_b span; ALL dead after scan_c: xin_b after
    // conv, z_b/xc_b/dt_b after scan_c, partb after reduce_xdbl). Ends at
    // 27,590,656 < yb(31,784,960), and yb/wout_b (G7 inputs) untouched.
    __hip_bfloat16* wout_b = (__hip_bfloat16*)(ws);              // 1,048,576 f
    __hip_bfloat16* win_b  = (__hip_bfloat16*)(ws + 1048576);    // 2,097,152 f
    __hip_bfloat16* xh_b   = (__hip_bfloat16*)(ws + 3145728);    // 2,097,152 f
    __hip_bfloat16* whf_b  = (__hip_bfloat16*)(ws + 5242880);    //   524,288 f
    __hip_bfloat16* m_b    = (__hip_bfloat16*)(ws + 5767168);    // 2,097,152 f
    __hip_bfloat16* hloc   = (__hip_bfloat16*)(ws + 1048576);    // scan overlay
    __hip_bfloat16* Pp     = (__hip_bfloat16*)(ws + 3145728);    // scan overlay
    __hip_bfloat16* h0     = (__hip_bfloat16*)(ws + 5242880);    // scan overlay
    __hip_bfloat16* wx_b   = (__hip_bfloat16*)(ws + 7864320);    //   131,072 f
    __hip_bfloat16* wdt_b  = (__hip_bfloat16*)(ws + 7995392);    //    65,536 f
    __hip_bfloat16* dtr_b  = (__hip_bfloat16*)(ws + 8060928);    //   131,072 f
    float*          xdbl   = ws + 10289152;                      //   524,288 f
    __hip_bfloat16* xin_b  = (__hip_bfloat16*)(ws + 10813440);   // 4,194,304 f
    __hip_bfloat16* z_b    = (__hip_bfloat16*)(ws + 15007744);   // 4,194,304 f
    __hip_bfloat16* xc_b   = (__hip_bfloat16*)(ws + 19202048);   // 4,194,304 f
    __hip_bfloat16* partb  = (__hip_bfloat16*)(ws + 23396352);   // G4 bf16 partials
    __hip_bfloat16* dt_b   = (__hip_bfloat16*)(ws + 27590656);   // 4,194,304 f
    __hip_bfloat16* part8b = (__hip_bfloat16*)(ws + 10813440);   // G7 overlay
    __hip_bfloat16* yb     = (__hip_bfloat16*)(ws + 31784960);   // 4,194,304 f

    // 0. pre-convert all static operands to bf16 (one fused launch)
    cvt_all<<<11648, 256, 0, stream>>>(
        W_out, W_in, x_h, W_hf, W_x, W_dt,
        wout_b, win_b, xh_b, whf_b, wx_b, wdt_b);

    // 1. m_b = bf16( x_f * sigmoid(x_h @ W_hf^T + b_hf) )  (SWAP XCD pin)
    mfma_gemm<1, true><<<dim3(32, 8, 1), 256, 0, stream>>>(
        xh_b, DMODEL, whf_b, DMODEL, DMODEL,
        nullptr, DMODEL, m_b, b_hf, x_f, DMODEL);

    // 2. [x_in | z] = m @ W_in^T  (256^2 tile, KB=64 + T2 swizzle + T5)
    mfma_gemm256<2, 64><<<dim3(16, 16, 1), 512, 0, stream>>>(
        m_b, DMODEL, win_b, DMODEL, DMODEL, xin_b, z_b);

    // 3. xc_b = bf16( silu(causal_conv4(x_in) + conv_b) )  4e/thread
    conv_silu_kernel<<<8192, 256, 0, stream>>>(
        xin_b, conv_w, conv_b, xc_b);

    // 4. x_dbl = xc @ W_x^T (padded N=128, split-K 8, bf16 partials) + reduce
    mfma_gemm<5, false><<<dim3(1, 32, 8), 256, 0, stream>>>(
        xc_b, DINNER, wx_b, DINNER, 256,
        nullptr, 128, partb, nullptr, nullptr, 0);
    reduce_xdbl<<<2048, 256, 0, stream>>>(partb, xdbl, dtr_b);

    // 5. dt_b = bf16( softplus(dt_r @ W_dt^T + b_dt) )
    mfma_gemm<3, false><<<dim3(16, 32, 1), 256, 0, stream>>>(
        dtr_b, 64, wdt_b, 64, 64,
        nullptr, 2048, dt_b, b_dt, nullptr, 0);

    // 6. chunked scan (lane-owns-channel, NCHUNK=64)
    scan_pass_a<<<dim3(8, NCHUNK - 1, BATCH), 256, 0, stream>>>(
        dt_b, xc_b, xdbl, A_log, hloc, Pp);
    scan_pass_b<<<256, 256, 0, stream>>>(hloc, Pp, h0);
    scan_pass_c<<<dim3(8, NCHUNK, BATCH), 256, 0, stream>>>(
        dt_b, xc_b, xdbl, z_b, A_log, Dw, h0, yb);

    // 7. out = y @ W_out^T: 256^2 kernel, KB=32 (64KB LDS -> 2 blocks/CU),
    //    split-K=8 (512 blocks); bf16 partials into part8b, 8-slice reduce.
    mfma_gemm256<4, 32><<<dim3(4, 16, 8), 512, 0, stream>>>(
        yb, DINNER, wout_b, DINNER, DINNER / 8, part8b, nullptr);
    reduce_out8<<<4096, 256, 0, stream>>>(part8b, out);
}

// Round 20
// 261.900 us; speedup vs baseline: 1.0528x; 1.0528x over previous
//
#include <hip/hip_runtime.h>
#include <hip/hip_bf16.h>
#include <math.h>

#define L_SEQ  2048
#define BATCH  2
#define DMODEL 1024
#define DINNER 2048
#define DSTATE 16
#define NCHUNK 64
#define LCH    (L_SEQ / NCHUNK)  // 32

typedef __attribute__((ext_vector_type(8))) short bf16x8;
typedef __attribute__((ext_vector_type(4))) float f32x4;

__device__ __forceinline__ unsigned short f2bu(float x) {
    __hip_bfloat16 h = __float2bfloat16(x);
    return __builtin_bit_cast(unsigned short, h);
}
__device__ __forceinline__ float bu2f(unsigned short u) {
    __hip_bfloat16 h = __builtin_bit_cast(__hip_bfloat16, u);
    return __bfloat162float(h);
}
// v_exp_f32: D = 2^S0 (hardware exp2)
__device__ __forceinline__ float fast_exp2(float x) {
    float r; asm("v_exp_f32 %0, %1" : "=v"(r) : "v"(x)); return r;
}
#define LOG2E 1.44269504088896f

// ---------------------------------------------------------------------------
// Fused fp32 -> bf16 conversion for all static operands (one launch).
// ---------------------------------------------------------------------------
__global__ __launch_bounds__(256) void cvt_all(
    const float* __restrict__ Wout, const float* __restrict__ Win,
    const float* __restrict__ xh,   const float* __restrict__ Whf,
    const float* __restrict__ Wx,   const float* __restrict__ Wdt,
    __hip_bfloat16* __restrict__ dWout, __hip_bfloat16* __restrict__ dWin,
    __hip_bfloat16* __restrict__ dxh,   __hip_bfloat16* __restrict__ dWhf,
    __hip_bfloat16* __restrict__ dWx,   __hip_bfloat16* __restrict__ dWdt)
{
    int bid = blockIdx.x;
    const float* s; __hip_bfloat16* d;
    if (bid < 2048)       { s = Wout; d = dWout; }
    else if (bid < 6144)  { s = Win;  d = dWin;  bid -= 2048; }
    else if (bid < 10240) { s = xh;   d = dxh;   bid -= 6144; }
    else if (bid < 11264) { s = Whf;  d = dWhf;  bid -= 10240; }
    else if (bid < 11520) {
        // W_x (96x2048) -> 128x2048, rows 96..127 zero
        bid -= 11264;
        const int i = (bid * 256 + threadIdx.x) * 4;
        const int r = i >> 11;
        ushort4 u = {0, 0, 0, 0};
        if (r < 96) {
            const float4 v = *reinterpret_cast<const float4*>(&Wx[i]);
            u.x = f2bu(v.x); u.y = f2bu(v.y); u.z = f2bu(v.z); u.w = f2bu(v.w);
        }
        *reinterpret_cast<ushort4*>(&dWx[i]) = u;
        return;
    }
    else                  { s = Wdt;  d = dWdt;  bid -= 11520; }
    const int i = (bid * 256 + threadIdx.x) * 4;
    const float4 v = *reinterpret_cast<const float4*>(&s[i]);
    ushort4 u;
    u.x = f2bu(v.x); u.y = f2bu(v.y); u.z = f2bu(v.z); u.w = f2bu(v.w);
    *reinterpret_cast<ushort4*>(&d[i]) = u;
}

// ---------------------------------------------------------------------------
// 256x256-tile MFMA bf16 GEMM (T2-swizzled, conflict-free; R16-verified).
// 8 waves (2Mx4N), BK=64, 64 MFMA/wave/K-step, dbuf 128KB LDS, prefetch-early
// + single __syncthreads per K-step. T5 setprio wraps the MFMA cluster.
// EPI 2: bf16 split planes (col<2048 -> Cb=x_in else Cb2=z), G2.
// EPI 4: bf16 split-K partials: Cb + z*(rows*ncols), G7.
// ---------------------------------------------------------------------------
template <int EPI>
__global__ __launch_bounds__(512) void mfma_gemm256(
    const __hip_bfloat16* __restrict__ A, int lda,
    const __hip_bfloat16* __restrict__ Bw, int ldb,
    int ksz,
    __hip_bfloat16* __restrict__ Cb,
    __hip_bfloat16* __restrict__ Cb2)
{
    __shared__ unsigned short As[2][256 * 64];
    __shared__ unsigned short Bs[2][256 * 64];
    const int tid = threadIdx.x;
    const int row0 = blockIdx.y * 256;
    const int col0 = blockIdx.x * 256;
    const int wid = tid >> 6, lane = tid & 63;
    const int wr = wid >> 2, wc = wid & 3;
    const int fr = lane & 15, fq = lane >> 4;
    const int kz0 = blockIdx.z * ksz;
    const int nk = ksz >> 6;

    f32x4 acc[8][4];
#pragma unroll
    for (int m = 0; m < 8; m++)
#pragma unroll
        for (int n = 0; n < 4; n++) acc[m][n] = (f32x4){0.f, 0.f, 0.f, 0.f};

    // staging: 2048 16B-items per operand; item -> LDS row r=item>>3,
    // chunk sl=item&7 (linear dest). SOURCE chunk = sl ^ (r&7)  [T2 swizzle].
    size_t gA[4], gB[4];
    int ld0[4];
#pragma unroll
    for (int l = 0; l < 4; l++) {
        const int item = l * 512 + tid;
        const int r = item >> 3, sl = item & 7;
        const int slw = sl ^ (r & 7);
        gA[l] = (size_t)(row0 + r) * lda + slw * 8;
        gB[l] = (size_t)(col0 + r) * ldb + slw * 8;
        ld0[l] = item * 8;
    }

#if __has_builtin(__builtin_amdgcn_global_load_lds)
    auto STAGE = [&](int buf, int koff) {
#pragma unroll
        for (int l = 0; l < 4; l++)
            __builtin_amdgcn_global_load_lds(
                (const __attribute__((address_space(1))) unsigned int*)(A + gA[l] + koff),
                (__attribute__((address_space(3))) unsigned int*)&As[buf][ld0[l]], 16, 0, 0);
#pragma unroll
        for (int l = 0; l < 4; l++)
            __builtin_amdgcn_global_load_lds(
                (const __attribute__((address_space(1))) unsigned int*)(Bw + gB[l] + koff),
                (__attribute__((address_space(3))) unsigned int*)&Bs[buf][ld0[l]], 16, 0, 0);
    };
#else
    auto STAGE = [&](int buf, int koff) {
#pragma unroll
        for (int l = 0; l < 4; l++) {
            *reinterpret_cast<uint4*>(&As[buf][ld0[l]]) =
                *reinterpret_cast<const uint4*>(A + gA[l] + koff);
            *reinterpret_cast<uint4*>(&Bs[buf][ld0[l]]) =
                *reinterpret_cast<const uint4*>(Bw + gB[l] + koff);
        }
    };
#endif

    STAGE(0, kz0);
    __syncthreads();
    int buf = 0;
    const int swz = fr & 7;   // row&7 for rows base+fr (base multiple of 16)
    for (int t = 0; t < nk; t++) {
        if (t + 1 < nk) STAGE(buf ^ 1, kz0 + (t + 1) * 64);
#pragma unroll
        for (int ks = 0; ks < 2; ks++) {
            bf16x8 a[8], b[4];
#pragma unroll
            for (int m = 0; m < 8; m++)
                a[m] = *reinterpret_cast<const bf16x8*>(
                    &As[buf][(wr * 128 + m * 16 + fr) * 64 +
                             (((ks * 4 + fq) ^ swz) * 8)]);
#pragma unroll
            for (int n = 0; n < 4; n++)
                b[n] = *reinterpret_cast<const bf16x8*>(
                    &Bs[buf][(wc * 64 + n * 16 + fr) * 64 +
                             (((ks * 4 + fq) ^ swz) * 8)]);
            __builtin_amdgcn_s_setprio(1);     // T5
#pragma unroll
            for (int m = 0; m < 8; m++)
#pragma unroll
                for (int n = 0; n < 4; n++)
                    acc[m][n] = __builtin_amdgcn_mfma_f32_16x16x32_bf16(
                        a[m], b[n], acc[m][n], 0, 0, 0);
            __builtin_amdgcn_s_setprio(0);
        }
        __syncthreads();
        buf ^= 1;
    }

    // C/D layout: col = lane&15, row = (lane>>4)*4 + reg
    const int r0 = row0 + wr * 128;
    const int c0 = col0 + wc * 64;
    const bool isx = (col0 < 2048);
    const int ncols = gridDim.x * 256;
    __hip_bfloat16* pz = Cb +
        (size_t)blockIdx.z * (size_t)(gridDim.y * 256) * ncols;
#pragma unroll
    for (int m = 0; m < 8; m++)
#pragma unroll
        for (int n = 0; n < 4; n++) {
            const int col = c0 + n * 16 + fr;
#pragma unroll
            for (int j = 0; j < 4; j++) {
                const int row = r0 + m * 16 + fq * 4 + j;
                const __hip_bfloat16 v = __float2bfloat16(acc[m][n][j]);
                if (EPI == 2) {
                    if (isx) Cb[(size_t)row * 2048 + col] = v;
                    else     Cb2[(size_t)row * 2048 + col - 2048] = v;
                } else {
                    pz[(size_t)row * ncols + col] = v;
                }
            }
        }
}

// ---------------------------------------------------------------------------
// MFMA bf16 GEMM: 128x128 tile, BK=32, 4 waves, 2-barrier loop.
// SWAP: blockIdx.x = ROW-block (XCD panel pinning for skinny-N G1).
// EPI: 0 fp32 C; 1 bf16 C = sigmoid(acc+bias)*mul; 3 bf16 softplus(acc+bias);
//      5 bf16 split-K partials (Cb + z*rows*ldc).
// ---------------------------------------------------------------------------
template <int EPI, bool SWAP>
__global__ __launch_bounds__(256) void mfma_gemm(
    const __hip_bfloat16* __restrict__ A, int lda,
    const __hip_bfloat16* __restrict__ Bw, int ldb,
    int ksz,
    float* __restrict__ Cf, int ldc,
    __hip_bfloat16* __restrict__ Cb,
    const float* __restrict__ bias,
    const float* __restrict__ mul, int ldmul)
{
    __shared__ unsigned short As[128 * 32];
    __shared__ unsigned short Bs[128 * 32];
    const int tid = threadIdx.x;
    const int by = SWAP ? blockIdx.x : blockIdx.y;   // row-block
    const int bx = SWAP ? blockIdx.y : blockIdx.x;   // col-block
    const int row0 = by * 128;
    const int col0 = bx * 128;
    const int wid = tid >> 6, lane = tid & 63;
    const int wr = wid >> 1, wc = wid & 1;
    const int fr = lane & 15, fq = lane >> 4;
    const int kz0 = blockIdx.z * ksz;

    f32x4 acc[4][4];
#pragma unroll
    for (int i = 0; i < 4; i++)
#pragma unroll
        for (int j = 0; j < 4; j++) acc[i][j] = (f32x4){0.f, 0.f, 0.f, 0.f};

    const int i0 = tid, i1 = tid + 256;
    const size_t ga0 = (size_t)(row0 + (i0 >> 2)) * lda + (i0 & 3) * 8;
    const size_t ga1 = (size_t)(row0 + (i1 >> 2)) * lda + (i1 & 3) * 8;
    const size_t gb0 = (size_t)(col0 + (i0 >> 2)) * ldb + (i0 & 3) * 8;
    const size_t gb1 = (size_t)(col0 + (i1 >> 2)) * ldb + (i1 & 3) * 8;
    const int nk = ksz >> 5;

    for (int kk = 0; kk < nk; kk++) {
        const int koff = kz0 + kk * 32;
#if __has_builtin(__builtin_amdgcn_global_load_lds)
        __syncthreads();   // readers of previous tile done
        __builtin_amdgcn_global_load_lds(
            (const __attribute__((address_space(1))) unsigned int*)(A + ga0 + koff),
            (__attribute__((address_space(3))) unsigned int*)&As[i0 * 8], 16, 0, 0);
        __builtin_amdgcn_global_load_lds(
            (const __attribute__((address_space(1))) unsigned int*)(A + ga1 + koff),
            (__attribute__((address_space(3))) unsigned int*)&As[i1 * 8], 16, 0, 0);
        __builtin_amdgcn_global_load_lds(
            (const __attribute__((address_space(1))) unsigned int*)(Bw + gb0 + koff),
            (__attribute__((address_space(3))) unsigned int*)&Bs[i0 * 8], 16, 0, 0);
        __builtin_amdgcn_global_load_lds(
            (const __attribute__((address_space(1))) unsigned int*)(Bw + gb1 + koff),
            (__attribute__((address_space(3))) unsigned int*)&Bs[i1 * 8], 16, 0, 0);
        __syncthreads();   // staged tile visible (vmcnt drained by barrier)
#else
        const uint4 va0 = *reinterpret_cast<const uint4*>(A + ga0 + koff);
        const uint4 va1 = *reinterpret_cast<const uint4*>(A + ga1 + koff);
        const uint4 vb0 = *reinterpret_cast<const uint4*>(Bw + gb0 + koff);
        const uint4 vb1 = *reinterpret_cast<const uint4*>(Bw + gb1 + koff);
        __syncthreads();
        *reinterpret_cast<uint4*>(&As[i0 * 8]) = va0;
        *reinterpret_cast<uint4*>(&As[i1 * 8]) = va1;
        *reinterpret_cast<uint4*>(&Bs[i0 * 8]) = vb0;
        *reinterpret_cast<uint4*>(&Bs[i1 * 8]) = vb1;
        __syncthreads();
#endif
        bf16x8 af[4], bq[4];
#pragma unroll
        for (int rb = 0; rb < 4; rb++)
            af[rb] = *reinterpret_cast<const bf16x8*>(
                &As[(wr * 64 + rb * 16 + fr) * 32 + fq * 8]);
#pragma unroll
        for (int cb = 0; cb < 4; cb++)
            bq[cb] = *reinterpret_cast<const bf16x8*>(
                &Bs[(wc * 64 + cb * 16 + fr) * 32 + fq * 8]);
#pragma unroll
        for (int rb = 0; rb < 4; rb++)
#pragma unroll
            for (int cb = 0; cb < 4; cb++)
                acc[rb][cb] = __builtin_amdgcn_mfma_f32_16x16x32_bf16(
                    af[rb], bq[cb], acc[rb][cb], 0, 0, 0);
    }

    // C/D layout: col = lane&15, row = (lane>>4)*4 + reg
    const int nrows = (SWAP ? gridDim.x : gridDim.y) * 128;
    float* Cz = Cf + (EPI == 0 ?
        (size_t)blockIdx.z * (size_t)nrows * ldc : 0);
    __hip_bfloat16* Cbz = Cb + (EPI == 5 ?
        (size_t)blockIdx.z * (size_t)nrows * ldc : 0);
    const int r0 = row0 + wr * 64, c0 = col0 + wc * 64;
#pragma unroll
    for (int rb = 0; rb < 4; rb++)
#pragma unroll
        for (int cb = 0; cb < 4; cb++) {
            const int col = c0 + cb * 16 + fr;
#pragma unroll
            for (int j = 0; j < 4; j++) {
                const int row = r0 + rb * 16 + fq * 4 + j;
                float v = acc[rb][cb][j];
                if (EPI == 0) {
                    Cz[(size_t)row * ldc + col] = v;
                } else if (EPI == 1) {
                    v = 1.f / (1.f + __expf(-(v + bias[col])));
                    v *= mul[(size_t)row * ldmul + col];
                    Cb[(size_t)row * ldc + col] = __float2bfloat16(v);
                } else if (EPI == 5) {
                    Cbz[(size_t)row * ldc + col] = __float2bfloat16(v);
                } else {
                    v += bias[col];
                    v = (v > 20.f) ? v : log1pf(__expf(v));
                    Cb[(size_t)row * ldc + col] = __float2bfloat16(v);
                }
            }
        }
}

// Split-K reduce for x_dbl (bf16 partials, 8 slices of 4096x128), emits
// fp32 xdbl + bf16 dt_r.
__global__ __launch_bounds__(256) void reduce_xdbl(
    const __hip_bfloat16* __restrict__ part, float* __restrict__ xdbl,
    __hip_bfloat16* __restrict__ dtr)
{
    const int i = blockIdx.x * 256 + threadIdx.x;   // 4096*128
    float s = 0.f;
#pragma unroll
    for (int j = 0; j < 8; j++)
        s += __bfloat162float(part[(size_t)j * 524288 + i]);
    xdbl[i] = s;
    const int col = i & 127;
    if (col < 64) dtr[((i >> 7) << 6) + col] = __float2bfloat16(s);
}

// G7 split-K=4 reduce: out = sum of 4 bf16 partial slices -> fp32. vec4.
__global__ __launch_bounds__(256) void reduce_out4(
    const __hip_bfloat16* __restrict__ part, float* __restrict__ out)
{
    const int i = (blockIdx.x * 256 + threadIdx.x) * 4;   // 4,194,304 elems
    float s0 = 0.f, s1 = 0.f, s2 = 0.f, s3 = 0.f;
#pragma unroll
    for (int z = 0; z < 4; z++) {
        const ushort4 u = *reinterpret_cast<const ushort4*>(
            &part[(size_t)z * 4194304 + i]);
        s0 += bu2f(u.x); s1 += bu2f(u.y); s2 += bu2f(u.z); s3 += bu2f(u.w);
    }
    *reinterpret_cast<float4*>(&out[i]) = make_float4(s0, s1, s2, s3);
}

// ---------------------------------------------------------------------------
// Depthwise causal conv (width 4) + bias + SiLU, 4 consecutive e per thread.
// Per-thread weights cw[e*4..e*4+16) are one contiguous 64B block (4x float4,
// coalesced across lanes); x loads are ushort4 (8B/lane, coalesced).
// Grid: 4096 rows x 2 e-halves = 8192.
// ---------------------------------------------------------------------------
__global__ __launch_bounds__(256) void conv_silu_kernel(
    const __hip_bfloat16* __restrict__ xin_b, const float* __restrict__ cw,
    const float* __restrict__ cb, __hip_bfloat16* __restrict__ xcb)
{
    const int bid = blockIdx.x;
    const int row = bid >> 1;
    const int e = ((bid & 1) << 10) + threadIdx.x * 4;
    const int t = row & (L_SEQ - 1);
    float w[16];
    *(float4*)&w[0]  = *(const float4*)&cw[e * 4];
    *(float4*)&w[4]  = *(const float4*)&cw[e * 4 + 4];
    *(float4*)&w[8]  = *(const float4*)&cw[e * 4 + 8];
    *(float4*)&w[12] = *(const float4*)&cw[e * 4 + 12];
    const float4 bias = *(const float4*)&cb[e];
    float s0 = bias.x, s1 = bias.y, s2 = bias.z, s3 = bias.w;
#pragma unroll
    for (int j = 0; j < 4; j++) {
        const int tt = t - 3 + j;
        if (tt >= 0) {
            const ushort4 xv = *(const ushort4*)&xin_b[
                (size_t)(row - 3 + j) * 2048 + e];
            s0 = fmaf(w[j],      bu2f(xv.x), s0);
            s1 = fmaf(w[4 + j],  bu2f(xv.y), s1);
            s2 = fmaf(w[8 + j],  bu2f(xv.z), s2);
            s3 = fmaf(w[12 + j], bu2f(xv.w), s3);
        }
    }
    ushort4 o;
    o.x = f2bu(s0 / (1.f + __expf(-s0)));
    o.y = f2bu(s1 / (1.f + __expf(-s1)));
    o.z = f2bu(s2 / (1.f + __expf(-s2)));
    o.w = f2bu(s3 / (1.f + __expf(-s3)));
    *(ushort4*)&xcb[(size_t)row * 2048 + e] = o;
}

// ---------------------------------------------------------------------------
// Chunked selective scan, lane-owns-channel layout. NCHUNK=64, LCH=32.
// ---------------------------------------------------------------------------
__global__ __launch_bounds__(256) void scan_pass_a(
    const __hip_bfloat16* __restrict__ dtb, const __hip_bfloat16* __restrict__ xcb,
    const float* __restrict__ xdbl, const float* __restrict__ A_log,
    __hip_bfloat16* __restrict__ hloc, __hip_bfloat16* __restrict__ Pp)
{
    __shared__ float sB[LCH][16];
    const int tid = threadIdx.x;
    const int e = (blockIdx.x << 8) + tid;
    const int chunk = blockIdx.y;             // 0..NCHUNK-2
    const int b = blockIdx.z;
    const int t0 = chunk * LCH;

    if (tid < LCH * 4) {
        const int r = tid >> 2, sl = tid & 3;
        *(float4*)&sB[r][sl * 4] =
            *(const float4*)&xdbl[(size_t)(b * L_SEQ + t0 + r) * 128 + 64 + sl * 4];
    }
    float av[16];
#pragma unroll
    for (int sq = 0; sq < 4; sq++) {
        const float4 al = *(const float4*)&A_log[e * 16 + sq * 4];
#pragma unroll
        for (int j = 0; j < 4; j++)
            av[sq * 4 + j] = -fast_exp2(((const float*)&al)[j] * LOG2E);
    }
    float h[16];
#pragma unroll
    for (int s = 0; s < 16; s++) h[s] = 0.f;
    float sdt = 0.f;
    __syncthreads();

    const size_t rb = (size_t)(b * L_SEQ + t0) * 2048 + e;
    float dtv_n = __bfloat162float(dtb[rb]);
    float xv_n = __bfloat162float(xcb[rb]);
    for (int t = 0; t < LCH; t++) {
        const float dtv = dtv_n, xv = xv_n;
        if (t + 1 < LCH) {
            dtv_n = __bfloat162float(dtb[rb + (size_t)(t + 1) * 2048]);
            xv_n = __bfloat162float(xcb[rb + (size_t)(t + 1) * 2048]);
        }
        sdt += dtv;
        const float dtx = dtv * xv;
        const float dl2 = dtv * LOG2E;
#pragma unroll
        for (int sq = 0; sq < 4; sq++) {
            const float4 B4 = *(const float4*)&sB[t][sq * 4];
#pragma unroll
            for (int j = 0; j < 4; j++) {
                const int s = sq * 4 + j;
                const float Bv = ((const float*)&B4)[j];
                h[s] = fmaf(fast_exp2(dl2 * av[s]), h[s], Bv * dtx);
            }
        }
    }
    const size_t o = (((size_t)chunk * BATCH + b) * 2048 + e) * 16;
#pragma unroll
    for (int sq = 0; sq < 4; sq++) {
        ushort4 uh, up;
        uh.x = f2bu(h[sq * 4]);     uh.y = f2bu(h[sq * 4 + 1]);
        uh.z = f2bu(h[sq * 4 + 2]); uh.w = f2bu(h[sq * 4 + 3]);
        up.x = f2bu(fast_exp2(av[sq * 4] * sdt * LOG2E));
        up.y = f2bu(fast_exp2(av[sq * 4 + 1] * sdt * LOG2E));
        up.z = f2bu(fast_exp2(av[sq * 4 + 2] * sdt * LOG2E));
        up.w = f2bu(fast_exp2(av[sq * 4 + 3] * sdt * LOG2E));
        *(ushort4*)&hloc[o + sq * 4] = uh;
        *(ushort4*)&Pp[o + sq * 4] = up;
    }
}

__global__ __launch_bounds__(256) void scan_pass_b(
    const __hip_bfloat16* __restrict__ hloc, const __hip_bfloat16* __restrict__ Pp,
    __hip_bfloat16* __restrict__ h0)
{
    const int idx = blockIdx.x * 256 + threadIdx.x;   // 65536
    float h = 0.f;
    h0[idx] = __float2bfloat16(0.f);
    for (int c = 0; c < NCHUNK - 1; c++) {
        const float P = __bfloat162float(Pp[(size_t)c * 65536 + idx]);
        const float hl = __bfloat162float(hloc[(size_t)c * 65536 + idx]);
        h = fmaf(P, h, hl);
        h0[(size_t)(c + 1) * 65536 + idx] = __float2bfloat16(h);
    }
}

__global__ __launch_bounds__(256) void scan_pass_c(
    const __hip_bfloat16* __restrict__ dtb, const __hip_bfloat16* __restrict__ xcb,
    const float* __restrict__ xdbl, const __hip_bfloat16* __restrict__ zb,
    const float* __restrict__ A_log, const float* __restrict__ Dw,
    const __hip_bfloat16* __restrict__ h0, __hip_bfloat16* __restrict__ yb)
{
    __shared__ float sB[LCH][16];
    __shared__ float sC[LCH][16];
    const int tid = threadIdx.x;
    const int e = (blockIdx.x << 8) + tid;
    const int chunk = blockIdx.y;
    const int b = blockIdx.z;
    const int t0 = chunk * LCH;

    if (tid < LCH * 4) {
        const int r = tid >> 2, sl = tid & 3;
        *(float4*)&sB[r][sl * 4] =
            *(const float4*)&xdbl[(size_t)(b * L_SEQ + t0 + r) * 128 + 64 + sl * 4];
    } else if (tid < LCH * 8) {
        const int t2 = tid - LCH * 4;
        const int r = t2 >> 2, sl = t2 & 3;
        *(float4*)&sC[r][sl * 4] =
            *(const float4*)&xdbl[(size_t)(b * L_SEQ + t0 + r) * 128 + 80 + sl * 4];
    }
    float av[16];
#pragma unroll
    for (int sq = 0; sq < 4; sq++) {
        const float4 al = *(const float4*)&A_log[e * 16 + sq * 4];
#pragma unroll
        for (int j = 0; j < 4; j++)
            av[sq * 4 + j] = -fast_exp2(((const float*)&al)[j] * LOG2E);
    }
    const float De = Dw[e];
    float h[16];
    const size_t o = (((size_t)chunk * BATCH + b) * 2048 + e) * 16;
#pragma unroll
    for (int sq = 0; sq < 4; sq++) {
        const ushort4 hv = *(const ushort4*)&h0[o + sq * 4];
        h[sq * 4]     = bu2f(hv.x); h[sq * 4 + 1] = bu2f(hv.y);
        h[sq * 4 + 2] = bu2f(hv.z); h[sq * 4 + 3] = bu2f(hv.w);
    }
    __syncthreads();

    const size_t rb = (size_t)(b * L_SEQ + t0) * 2048 + e;
    float dtv_n = __bfloat162float(dtb[rb]);
    float xv_n = __bfloat162float(xcb[rb]);
    float zv_n = __bfloat162float(zb[rb]);
    for (int t = 0; t < LCH; t++) {
        const float dtv = dtv_n, xv = xv_n, zv = zv_n;
        if (t + 1 < LCH) {
            dtv_n = __bfloat162float(dtb[rb + (size_t)(t + 1) * 2048]);
            xv_n = __bfloat162float(xcb[rb + (size_t)(t + 1) * 2048]);
            zv_n = __bfloat162float(zb[rb + (size_t)(t + 1) * 2048]);
        }
        const float dtx = dtv * xv;
        const float dl2 = dtv * LOG2E;
        float yp0 = 0.f, yp1 = 0.f, yp2 = 0.f, yp3 = 0.f;
#pragma unroll
        for (int sq = 0; sq < 4; sq++) {
            const float4 B4 = *(const float4*)&sB[t][sq * 4];
            const float4 C4 = *(const float4*)&sC[t][sq * 4];
#pragma unroll
            for (int j = 0; j < 4; j++) {
                const int s = sq * 4 + j;
                const float Bv = ((const float*)&B4)[j];
                const float Cv = ((const float*)&C4)[j];
                h[s] = fmaf(fast_exp2(dl2 * av[s]), h[s], Bv * dtx);
                if (sq == 0) yp0 = fmaf(h[s], Cv, yp0);
                else if (sq == 1) yp1 = fmaf(h[s], Cv, yp1);
                else if (sq == 2) yp2 = fmaf(h[s], Cv, yp2);
                else yp3 = fmaf(h[s], Cv, yp3);
            }
        }
        float yv = (yp0 + yp1) + (yp2 + yp3);
        yv = fmaf(De, xv, yv);
        const float sig = 1.f / (1.f + __expf(-zv));
        yb[rb + (size_t)t * 2048] = __float2bfloat16(yv * zv * sig);
    }
}

extern "C" void kernel_launch(void* const* d_in, const int* in_sizes, int n_in,
                              void* d_out, int out_size, void* d_ws, size_t ws_size,
                              hipStream_t stream)
{
    const float* x_f    = (const float*)d_in[0];
    const float* x_h    = (const float*)d_in[1];
    const float* W_hf   = (const float*)d_in[2];
    const float* b_hf   = (const float*)d_in[3];
    const float* W_in   = (const float*)d_in[4];
    const float* conv_w = (const float*)d_in[5];
    const float* conv_b = (const float*)d_in[6];
    const float* W_x    = (const float*)d_in[7];
    const float* W_dt   = (const float*)d_in[8];
    const float* b_dt   = (const float*)d_in[9];
    const float* A_log  = (const float*)d_in[10];
    const float* Dw     = (const float*)d_in[11];
    const float* W_out  = (const float*)d_in[12];
    float* out = (float*)d_out;
    float* ws  = (float*)d_ws;

    // Workspace (f32 units; total 35,979,264 f = 143.9 MB, proven-safe).
    // G4 bf16 partials (8 x 524288 bf16 = 2,097,152 f) live in the part
    // region; G7 bf16 partials (8,388,608 f) overlay part+dt_b (dead by G7).
    __hip_bfloat16* wout_b = (__hip_bfloat16*)(ws);              // 1,048,576 f
    __hip_bfloat16* win_b  = (__hip_bfloat16*)(ws + 1048576);    // 2,097,152 f
    __hip_bfloat16* xh_b   = (__hip_bfloat16*)(ws + 3145728);    // 2,097,152 f
    __hip_bfloat16* whf_b  = (__hip_bfloat16*)(ws + 5242880);    //   524,288 f
    __hip_bfloat16* m_b    = (__hip_bfloat16*)(ws + 5767168);    // 2,097,152 f
    __hip_bfloat16* hloc   = (__hip_bfloat16*)(ws + 1048576);    // scan overlay
    __hip_bfloat16* Pp     = (__hip_bfloat16*)(ws + 3145728);    // scan overlay
    __hip_bfloat16* h0     = (__hip_bfloat16*)(ws + 5242880);    // scan overlay
    __hip_bfloat16* wx_b   = (__hip_bfloat16*)(ws + 7864320);    //   131,072 f
    __hip_bfloat16* wdt_b  = (__hip_bfloat16*)(ws + 7995392);    //    65,536 f
    __hip_bfloat16* dtr_b  = (__hip_bfloat16*)(ws + 8060928);    //   131,072 f
    float*          xdbl   = ws + 10289152;                      //   524,288 f
    __hip_bfloat16* xin_b  = (__hip_bfloat16*)(ws + 10813440);   // 4,194,304 f
    __hip_bfloat16* z_b    = (__hip_bfloat16*)(ws + 15007744);   // 4,194,304 f
    __hip_bfloat16* xc_b   = (__hip_bfloat16*)(ws + 19202048);   // 4,194,304 f
    __hip_bfloat16* partb  = (__hip_bfloat16*)(ws + 23396352);   // G4 bf16 partials
    __hip_bfloat16* dt_b   = (__hip_bfloat16*)(ws + 27590656);   // 4,194,304 f
    __hip_bfloat16* part7b = (__hip_bfloat16*)(ws + 23396352);   // G7 overlay
    __hip_bfloat16* yb     = (__hip_bfloat16*)(ws + 31784960);   // 4,194,304 f

    // 0. pre-convert all static operands to bf16 (one fused launch)
    cvt_all<<<11648, 256, 0, stream>>>(
        W_out, W_in, x_h, W_hf, W_x, W_dt,
        wout_b, win_b, xh_b, whf_b, wx_b, wdt_b);

    // 1. m_b = bf16( x_f * sigmoid(x_h @ W_hf^T + b_hf) )  (SWAP XCD pin)
    mfma_gemm<1, true><<<dim3(32, 8, 1), 256, 0, stream>>>(
        xh_b, DMODEL, whf_b, DMODEL, DMODEL,
        nullptr, DMODEL, m_b, b_hf, x_f, DMODEL);

    // 2. [x_in | z] = m @ W_in^T  (256^2 tile + T2 swizzle + T5)
    mfma_gemm256<2><<<dim3(16, 16, 1), 512, 0, stream>>>(
        m_b, DMODEL, win_b, DMODEL, DMODEL, xin_b, z_b);

    // 3. xc_b = bf16( silu(causal_conv4(x_in) + conv_b) )  4e/thread
    conv_silu_kernel<<<8192, 256, 0, stream>>>(
        xin_b, conv_w, conv_b, xc_b);

    // 4. x_dbl = xc @ W_x^T (padded N=128, split-K 8, bf16 partials) + reduce
    mfma_gemm<5, false><<<dim3(1, 32, 8), 256, 0, stream>>>(
        xc_b, DINNER, wx_b, DINNER, 256,
        nullptr, 128, partb, nullptr, nullptr, 0);
    reduce_xdbl<<<2048, 256, 0, stream>>>(partb, xdbl, dtr_b);

    // 5. dt_b = bf16( softplus(dt_r @ W_dt^T + b_dt) )
    mfma_gemm<3, false><<<dim3(16, 32, 1), 256, 0, stream>>>(
        dtr_b, 64, wdt_b, 64, 64,
        nullptr, 2048, dt_b, b_dt, nullptr, 0);

    // 6. chunked scan (lane-owns-channel, NCHUNK=64)
    scan_pass_a<<<dim3(8, NCHUNK - 1, BATCH), 256, 0, stream>>>(
        dt_b, xc_b, xdbl, A_log, hloc, Pp);
    scan_pass_b<<<256, 256, 0, stream>>>(hloc, Pp, h0);
    scan_pass_c<<<dim3(8, NCHUNK, BATCH), 256, 0, stream>>>(
        dt_b, xc_b, xdbl, z_b, A_log, Dw, h0, yb);

    // 7. out = y @ W_out^T on the swizzled 256^2 kernel, split-K=4;
    //    bf16 partials into part7b (dead partb+dt_b), then 4-slice reduce.
    mfma_gemm256<4><<<dim3(4, 16, 4), 512, 0, stream>>>(
        yb, DINNER, wout_b, DINNER, DINNER / 4, part7b, nullptr);
    reduce_out4<<<4096, 256, 0, stream>>>(part7b, out);
}

// Round 21
// 261.266 us; speedup vs baseline: 1.0553x; 1.0024x over previous
//
#include <hip/hip_runtime.h>
#include <hip/hip_bf16.h>
#include <math.h>

#define L_SEQ  2048
#define BATCH  2
#define DMODEL 1024
#define DINNER 2048
#define DSTATE 16
#define NCHUNK 64
#define LCH    (L_SEQ / NCHUNK)  // 32

typedef __attribute__((ext_vector_type(8))) short bf16x8;
typedef __attribute__((ext_vector_type(4))) float f32x4;

__device__ __forceinline__ unsigned short f2bu(float x) {
    __hip_bfloat16 h = __float2bfloat16(x);
    return __builtin_bit_cast(unsigned short, h);
}
__device__ __forceinline__ float bu2f(unsigned short u) {
    __hip_bfloat16 h = __builtin_bit_cast(__hip_bfloat16, u);
    return __bfloat162float(h);
}
// v_exp_f32: D = 2^S0 (hardware exp2)
__device__ __forceinline__ float fast_exp2(float x) {
    float r; asm("v_exp_f32 %0, %1" : "=v"(r) : "v"(x)); return r;
}
#define LOG2E 1.44269504088896f

// ---------------------------------------------------------------------------
// Fused fp32 -> bf16 conversion for all static operands (one launch).
// ---------------------------------------------------------------------------
__global__ __launch_bounds__(256) void cvt_all(
    const float* __restrict__ Wout, const float* __restrict__ Win,
    const float* __restrict__ xh,   const float* __restrict__ Whf,
    const float* __restrict__ Wx,   const float* __restrict__ Wdt,
    __hip_bfloat16* __restrict__ dWout, __hip_bfloat16* __restrict__ dWin,
    __hip_bfloat16* __restrict__ dxh,   __hip_bfloat16* __restrict__ dWhf,
    __hip_bfloat16* __restrict__ dWx,   __hip_bfloat16* __restrict__ dWdt)
{
    int bid = blockIdx.x;
    const float* s; __hip_bfloat16* d;
    if (bid < 2048)       { s = Wout; d = dWout; }
    else if (bid < 6144)  { s = Win;  d = dWin;  bid -= 2048; }
    else if (bid < 10240) { s = xh;   d = dxh;   bid -= 6144; }
    else if (bid < 11264) { s = Whf;  d = dWhf;  bid -= 10240; }
    else if (bid < 11520) {
        // W_x (96x2048) -> 128x2048, rows 96..127 zero
        bid -= 11264;
        const int i = (bid * 256 + threadIdx.x) * 4;
        const int r = i >> 11;
        ushort4 u = {0, 0, 0, 0};
        if (r < 96) {
            const float4 v = *reinterpret_cast<const float4*>(&Wx[i]);
            u.x = f2bu(v.x); u.y = f2bu(v.y); u.z = f2bu(v.z); u.w = f2bu(v.w);
        }
        *reinterpret_cast<ushort4*>(&dWx[i]) = u;
        return;
    }
    else                  { s = Wdt;  d = dWdt;  bid -= 11520; }
    const int i = (bid * 256 + threadIdx.x) * 4;
    const float4 v = *reinterpret_cast<const float4*>(&s[i]);
    ushort4 u;
    u.x = f2bu(v.x); u.y = f2bu(v.y); u.z = f2bu(v.z); u.w = f2bu(v.w);
    *reinterpret_cast<ushort4*>(&d[i]) = u;
}

// ---------------------------------------------------------------------------
// 256x256-tile MFMA bf16 GEMM (T2-swizzled; R16-verified layout).
// 8 waves (2Mx4N), BK=64, 64 MFMA/wave/K-step, dbuf 128KB LDS.
// R21: counted-vmcnt DEPTH-2 pipeline (T4): tile t+2 staged at END of step t
// (after an explicit lgkmcnt(0)+barrier proving all waves' LDS reads of the
// buffer have RETIRED); end-of-step waits vmcnt(8) -- tile t+1's 8 loads
// retired, tile t+2's 8 remain in flight ACROSS the barrier. Load cover
// >= 1 full iteration (vs <1 compute phase with the __syncthreads drain).
// Tail: vmcnt(0) when no stage issued (avoids vacuous-count bug).
// All fences: asm volatile "memory" (full compiler fence) + sched_barrier(0)
// (pins register-only ops, rule 18); barriers block-uniform. Requires nk>=2
// (G2 nk=16, G7 nk=8).
// EPI 2: bf16 split planes (col<2048 -> Cb=x_in else Cb2=z), G2.
// EPI 4: bf16 split-K partials: Cb + z*(rows*ncols), G7.
// ---------------------------------------------------------------------------
template <int EPI>
__global__ __launch_bounds__(512) void mfma_gemm256(
    const __hip_bfloat16* __restrict__ A, int lda,
    const __hip_bfloat16* __restrict__ Bw, int ldb,
    int ksz,
    __hip_bfloat16* __restrict__ Cb,
    __hip_bfloat16* __restrict__ Cb2)
{
    __shared__ unsigned short As[2][256 * 64];
    __shared__ unsigned short Bs[2][256 * 64];
    const int tid = threadIdx.x;
    const int row0 = blockIdx.y * 256;
    const int col0 = blockIdx.x * 256;
    const int wid = tid >> 6, lane = tid & 63;
    const int wr = wid >> 2, wc = wid & 3;
    const int fr = lane & 15, fq = lane >> 4;
    const int kz0 = blockIdx.z * ksz;
    const int nk = ksz >> 6;

    f32x4 acc[8][4];
#pragma unroll
    for (int m = 0; m < 8; m++)
#pragma unroll
        for (int n = 0; n < 4; n++) acc[m][n] = (f32x4){0.f, 0.f, 0.f, 0.f};

    // staging: 2048 16B-items per operand; item -> LDS row r=item>>3,
    // chunk sl=item&7 (linear dest). SOURCE chunk = sl ^ (r&7)  [T2 swizzle].
    size_t gA[4], gB[4];
    int ld0[4];
#pragma unroll
    for (int l = 0; l < 4; l++) {
        const int item = l * 512 + tid;
        const int r = item >> 3, sl = item & 7;
        const int slw = sl ^ (r & 7);
        gA[l] = (size_t)(row0 + r) * lda + slw * 8;
        gB[l] = (size_t)(col0 + r) * ldb + slw * 8;
        ld0[l] = item * 8;
    }

#if __has_builtin(__builtin_amdgcn_global_load_lds)
    auto STAGE = [&](int buf, int koff) {
#pragma unroll
        for (int l = 0; l < 4; l++)
            __builtin_amdgcn_global_load_lds(
                (const __attribute__((address_space(1))) unsigned int*)(A + gA[l] + koff),
                (__attribute__((address_space(3))) unsigned int*)&As[buf][ld0[l]], 16, 0, 0);
#pragma unroll
        for (int l = 0; l < 4; l++)
            __builtin_amdgcn_global_load_lds(
                (const __attribute__((address_space(1))) unsigned int*)(Bw + gB[l] + koff),
                (__attribute__((address_space(3))) unsigned int*)&Bs[buf][ld0[l]], 16, 0, 0);
    };

    // Prologue: stage tiles 0 and 1; wait tile 0 only (tile 1 stays in flight).
    STAGE(0, kz0);
    STAGE(1, kz0 + 64);
    asm volatile("s_waitcnt vmcnt(8)" ::: "memory");
    __builtin_amdgcn_sched_barrier(0);
    __builtin_amdgcn_s_barrier();
    __builtin_amdgcn_sched_barrier(0);

    const int swz = fr & 7;   // row&7 for rows base+fr (base multiple of 16)
    for (int t = 0; t < nk; t++) {
        const int buf = t & 1;
        // ---- compute tile t (reads buf; compiler inserts lgkm waits) ----
#pragma unroll
        for (int ks = 0; ks < 2; ks++) {
            bf16x8 a[8], b[4];
#pragma unroll
            for (int m = 0; m < 8; m++)
                a[m] = *reinterpret_cast<const bf16x8*>(
                    &As[buf][(wr * 128 + m * 16 + fr) * 64 +
                             (((ks * 4 + fq) ^ swz) * 8)]);
#pragma unroll
            for (int n = 0; n < 4; n++)
                b[n] = *reinterpret_cast<const bf16x8*>(
                    &Bs[buf][(wc * 64 + n * 16 + fr) * 64 +
                             (((ks * 4 + fq) ^ swz) * 8)]);
            __builtin_amdgcn_s_setprio(1);     // T5
#pragma unroll
            for (int m = 0; m < 8; m++)
#pragma unroll
                for (int n = 0; n < 4; n++)
                    acc[m][n] = __builtin_amdgcn_mfma_f32_16x16x32_bf16(
                        a[m], b[n], acc[m][n], 0, 0, 0);
            __builtin_amdgcn_s_setprio(0);
        }
        // ---- barrier #1: ALL waves' LDS reads of buf RETIRED => buf free ----
        asm volatile("s_waitcnt lgkmcnt(0)" ::: "memory");
        __builtin_amdgcn_sched_barrier(0);
        __builtin_amdgcn_s_barrier();
        __builtin_amdgcn_sched_barrier(0);
        // ---- stage tile t+2 into the freed buffer (depth-2 prefetch) ----
        if (t + 2 < nk) STAGE(buf, kz0 + (t + 2) * 64);
        // ---- barrier #2: tile t+1 visible; t+2's loads stay in flight ----
        if (t + 1 < nk) {
            if (t + 2 < nk) {
                asm volatile("s_waitcnt vmcnt(8)" ::: "memory");
            } else {
                asm volatile("s_waitcnt vmcnt(0)" ::: "memory");
            }
            __builtin_amdgcn_sched_barrier(0);
            __builtin_amdgcn_s_barrier();
            __builtin_amdgcn_sched_barrier(0);
        }
    }
#else
    // Fallback (no global_load_lds): simple 2-barrier reg-staged loop.
    const int swz = fr & 7;
    for (int t = 0; t < nk; t++) {
        const int koff = kz0 + t * 64;
        uint4 va[4], vb[4];
#pragma unroll
        for (int l = 0; l < 4; l++) {
            va[l] = *reinterpret_cast<const uint4*>(A + gA[l] + koff);
            vb[l] = *reinterpret_cast<const uint4*>(Bw + gB[l] + koff);
        }
        __syncthreads();
#pragma unroll
        for (int l = 0; l < 4; l++) {
            *reinterpret_cast<uint4*>(&As[0][ld0[l]]) = va[l];
            *reinterpret_cast<uint4*>(&Bs[0][ld0[l]]) = vb[l];
        }
        __syncthreads();
#pragma unroll
        for (int ks = 0; ks < 2; ks++) {
            bf16x8 a[8], b[4];
#pragma unroll
            for (int m = 0; m < 8; m++)
                a[m] = *reinterpret_cast<const bf16x8*>(
                    &As[0][(wr * 128 + m * 16 + fr) * 64 +
                           (((ks * 4 + fq) ^ swz) * 8)]);
#pragma unroll
            for (int n = 0; n < 4; n++)
                b[n] = *reinterpret_cast<const bf16x8*>(
                    &Bs[0][(wc * 64 + n * 16 + fr) * 64 +
                           (((ks * 4 + fq) ^ swz) * 8)]);
#pragma unroll
            for (int m = 0; m < 8; m++)
#pragma unroll
                for (int n = 0; n < 4; n++)
                    acc[m][n] = __builtin_amdgcn_mfma_f32_16x16x32_bf16(
                        a[m], b[n], acc[m][n], 0, 0, 0);
        }
    }
#endif

    // C/D layout: col = lane&15, row = (lane>>4)*4 + reg
    const int r0 = row0 + wr * 128;
    const int c0 = col0 + wc * 64;
    const bool isx = (col0 < 2048);
    const int ncols = gridDim.x * 256;
    __hip_bfloat16* pz = Cb +
        (size_t)blockIdx.z * (size_t)(gridDim.y * 256) * ncols;
#pragma unroll
    for (int m = 0; m < 8; m++)
#pragma unroll
        for (int n = 0; n < 4; n++) {
            const int col = c0 + n * 16 + fr;
#pragma unroll
            for (int j = 0; j < 4; j++) {
                const int row = r0 + m * 16 + fq * 4 + j;
                const __hip_bfloat16 v = __float2bfloat16(acc[m][n][j]);
                if (EPI == 2) {
                    if (isx) Cb[(size_t)row * 2048 + col] = v;
                    else     Cb2[(size_t)row * 2048 + col - 2048] = v;
                } else {
                    pz[(size_t)row * ncols + col] = v;
                }
            }
        }
}

// ---------------------------------------------------------------------------
// MFMA bf16 GEMM: 128x128 tile, BK=32, 4 waves, 2-barrier loop.
// SWAP: blockIdx.x = ROW-block (XCD panel pinning for skinny-N G1).
// EPI: 0 fp32 C; 1 bf16 C = sigmoid(acc+bias)*mul; 3 bf16 softplus(acc+bias);
//      5 bf16 split-K partials (Cb + z*rows*ldc).
// ---------------------------------------------------------------------------
template <int EPI, bool SWAP>
__global__ __launch_bounds__(256) void mfma_gemm(
    const __hip_bfloat16* __restrict__ A, int lda,
    const __hip_bfloat16* __restrict__ Bw, int ldb,
    int ksz,
    float* __restrict__ Cf, int ldc,
    __hip_bfloat16* __restrict__ Cb,
    const float* __restrict__ bias,
    const float* __restrict__ mul, int ldmul)
{
    __shared__ unsigned short As[128 * 32];
    __shared__ unsigned short Bs[128 * 32];
    const int tid = threadIdx.x;
    const int by = SWAP ? blockIdx.x : blockIdx.y;   // row-block
    const int bx = SWAP ? blockIdx.y : blockIdx.x;   // col-block
    const int row0 = by * 128;
    const int col0 = bx * 128;
    const int wid = tid >> 6, lane = tid & 63;
    const int wr = wid >> 1, wc = wid & 1;
    const int fr = lane & 15, fq = lane >> 4;
    const int kz0 = blockIdx.z * ksz;

    f32x4 acc[4][4];
#pragma unroll
    for (int i = 0; i < 4; i++)
#pragma unroll
        for (int j = 0; j < 4; j++) acc[i][j] = (f32x4){0.f, 0.f, 0.f, 0.f};

    const int i0 = tid, i1 = tid + 256;
    const size_t ga0 = (size_t)(row0 + (i0 >> 2)) * lda + (i0 & 3) * 8;
    const size_t ga1 = (size_t)(row0 + (i1 >> 2)) * lda + (i1 & 3) * 8;
    const size_t gb0 = (size_t)(col0 + (i0 >> 2)) * ldb + (i0 & 3) * 8;
    const size_t gb1 = (size_t)(col0 + (i1 >> 2)) * ldb + (i1 & 3) * 8;
    const int nk = ksz >> 5;

    for (int kk = 0; kk < nk; kk++) {
        const int koff = kz0 + kk * 32;
#if __has_builtin(__builtin_amdgcn_global_load_lds)
        __syncthreads();   // readers of previous tile done
        __builtin_amdgcn_global_load_lds(
            (const __attribute__((address_space(1))) unsigned int*)(A + ga0 + koff),
            (__attribute__((address_space(3))) unsigned int*)&As[i0 * 8], 16, 0, 0);
        __builtin_amdgcn_global_load_lds(
            (const __attribute__((address_space(1))) unsigned int*)(A + ga1 + koff),
            (__attribute__((address_space(3))) unsigned int*)&As[i1 * 8], 16, 0, 0);
        __builtin_amdgcn_global_load_lds(
            (const __attribute__((address_space(1))) unsigned int*)(Bw + gb0 + koff),
            (__attribute__((address_space(3))) unsigned int*)&Bs[i0 * 8], 16, 0, 0);
        __builtin_amdgcn_global_load_lds(
            (const __attribute__((address_space(1))) unsigned int*)(Bw + gb1 + koff),
            (__attribute__((address_space(3))) unsigned int*)&Bs[i1 * 8], 16, 0, 0);
        __syncthreads();   // staged tile visible (vmcnt drained by barrier)
#else
        const uint4 va0 = *reinterpret_cast<const uint4*>(A + ga0 + koff);
        const uint4 va1 = *reinterpret_cast<const uint4*>(A + ga1 + koff);
        const uint4 vb0 = *reinterpret_cast<const uint4*>(Bw + gb0 + koff);
        const uint4 vb1 = *reinterpret_cast<const uint4*>(Bw + gb1 + koff);
        __syncthreads();
        *reinterpret_cast<uint4*>(&As[i0 * 8]) = va0;
        *reinterpret_cast<uint4*>(&As[i1 * 8]) = va1;
        *reinterpret_cast<uint4*>(&Bs[i0 * 8]) = vb0;
        *reinterpret_cast<uint4*>(&Bs[i1 * 8]) = vb1;
        __syncthreads();
#endif
        bf16x8 af[4], bq[4];
#pragma unroll
        for (int rb = 0; rb < 4; rb++)
            af[rb] = *reinterpret_cast<const bf16x8*>(
                &As[(wr * 64 + rb * 16 + fr) * 32 + fq * 8]);
#pragma unroll
        for (int cb = 0; cb < 4; cb++)
            bq[cb] = *reinterpret_cast<const bf16x8*>(
                &Bs[(wc * 64 + cb * 16 + fr) * 32 + fq * 8]);
#pragma unroll
        for (int rb = 0; rb < 4; rb++)
#pragma unroll
            for (int cb = 0; cb < 4; cb++)
                acc[rb][cb] = __builtin_amdgcn_mfma_f32_16x16x32_bf16(
                    af[rb], bq[cb], acc[rb][cb], 0, 0, 0);
    }

    // C/D layout: col = lane&15, row = (lane>>4)*4 + reg
    const int nrows = (SWAP ? gridDim.x : gridDim.y) * 128;
    float* Cz = Cf + (EPI == 0 ?
        (size_t)blockIdx.z * (size_t)nrows * ldc : 0);
    __hip_bfloat16* Cbz = Cb + (EPI == 5 ?
        (size_t)blockIdx.z * (size_t)nrows * ldc : 0);
    const int r0 = row0 + wr * 64, c0 = col0 + wc * 64;
#pragma unroll
    for (int rb = 0; rb < 4; rb++)
#pragma unroll
        for (int cb = 0; cb < 4; cb++) {
            const int col = c0 + cb * 16 + fr;
#pragma unroll
            for (int j = 0; j < 4; j++) {
                const int row = r0 + rb * 16 + fq * 4 + j;
                float v = acc[rb][cb][j];
                if (EPI == 0) {
                    Cz[(size_t)row * ldc + col] = v;
                } else if (EPI == 1) {
                    v = 1.f / (1.f + __expf(-(v + bias[col])));
                    v *= mul[(size_t)row * ldmul + col];
                    Cb[(size_t)row * ldc + col] = __float2bfloat16(v);
                } else if (EPI == 5) {
                    Cbz[(size_t)row * ldc + col] = __float2bfloat16(v);
                } else {
                    v += bias[col];
                    v = (v > 20.f) ? v : log1pf(__expf(v));
                    Cb[(size_t)row * ldc + col] = __float2bfloat16(v);
                }
            }
        }
}

// Split-K reduce for x_dbl (bf16 partials, 8 slices of 4096x128), emits
// fp32 xdbl + bf16 dt_r.
__global__ __launch_bounds__(256) void reduce_xdbl(
    const __hip_bfloat16* __restrict__ part, float* __restrict__ xdbl,
    __hip_bfloat16* __restrict__ dtr)
{
    const int i = blockIdx.x * 256 + threadIdx.x;   // 4096*128
    float s = 0.f;
#pragma unroll
    for (int j = 0; j < 8; j++)
        s += __bfloat162float(part[(size_t)j * 524288 + i]);
    xdbl[i] = s;
    const int col = i & 127;
    if (col < 64) dtr[((i >> 7) << 6) + col] = __float2bfloat16(s);
}

// G7 split-K=4 reduce: out = sum of 4 bf16 partial slices -> fp32. vec4.
__global__ __launch_bounds__(256) void reduce_out4(
    const __hip_bfloat16* __restrict__ part, float* __restrict__ out)
{
    const int i = (blockIdx.x * 256 + threadIdx.x) * 4;   // 4,194,304 elems
    float s0 = 0.f, s1 = 0.f, s2 = 0.f, s3 = 0.f;
#pragma unroll
    for (int z = 0; z < 4; z++) {
        const ushort4 u = *reinterpret_cast<const ushort4*>(
            &part[(size_t)z * 4194304 + i]);
        s0 += bu2f(u.x); s1 += bu2f(u.y); s2 += bu2f(u.z); s3 += bu2f(u.w);
    }
    *reinterpret_cast<float4*>(&out[i]) = make_float4(s0, s1, s2, s3);
}

// ---------------------------------------------------------------------------
// Depthwise causal conv (width 4) + bias + SiLU, 4 consecutive e per thread.
// ---------------------------------------------------------------------------
__global__ __launch_bounds__(256) void conv_silu_kernel(
    const __hip_bfloat16* __restrict__ xin_b, const float* __restrict__ cw,
    const float* __restrict__ cb, __hip_bfloat16* __restrict__ xcb)
{
    const int bid = blockIdx.x;
    const int row = bid >> 1;
    const int e = ((bid & 1) << 10) + threadIdx.x * 4;
    const int t = row & (L_SEQ - 1);
    float w[16];
    *(float4*)&w[0]  = *(const float4*)&cw[e * 4];
    *(float4*)&w[4]  = *(const float4*)&cw[e * 4 + 4];
    *(float4*)&w[8]  = *(const float4*)&cw[e * 4 + 8];
    *(float4*)&w[12] = *(const float4*)&cw[e * 4 + 12];
    const float4 bias = *(const float4*)&cb[e];
    float s0 = bias.x, s1 = bias.y, s2 = bias.z, s3 = bias.w;
#pragma unroll
    for (int j = 0; j < 4; j++) {
        const int tt = t - 3 + j;
        if (tt >= 0) {
            const ushort4 xv = *(const ushort4*)&xin_b[
                (size_t)(row - 3 + j) * 2048 + e];
            s0 = fmaf(w[j],      bu2f(xv.x), s0);
            s1 = fmaf(w[4 + j],  bu2f(xv.y), s1);
            s2 = fmaf(w[8 + j],  bu2f(xv.z), s2);
            s3 = fmaf(w[12 + j], bu2f(xv.w), s3);
        }
    }
    ushort4 o;
    o.x = f2bu(s0 / (1.f + __expf(-s0)));
    o.y = f2bu(s1 / (1.f + __expf(-s1)));
    o.z = f2bu(s2 / (1.f + __expf(-s2)));
    o.w = f2bu(s3 / (1.f + __expf(-s3)));
    *(ushort4*)&xcb[(size_t)row * 2048 + e] = o;
}

// ---------------------------------------------------------------------------
// Chunked selective scan, lane-owns-channel layout. NCHUNK=64, LCH=32.
// ---------------------------------------------------------------------------
__global__ __launch_bounds__(256) void scan_pass_a(
    const __hip_bfloat16* __restrict__ dtb, const __hip_bfloat16* __restrict__ xcb,
    const float* __restrict__ xdbl, const float* __restrict__ A_log,
    __hip_bfloat16* __restrict__ hloc, __hip_bfloat16* __restrict__ Pp)
{
    __shared__ float sB[LCH][16];
    const int tid = threadIdx.x;
    const int e = (blockIdx.x << 8) + tid;
    const int chunk = blockIdx.y;             // 0..NCHUNK-2
    const int b = blockIdx.z;
    const int t0 = chunk * LCH;

    if (tid < LCH * 4) {
        const int r = tid >> 2, sl = tid & 3;
        *(float4*)&sB[r][sl * 4] =
            *(const float4*)&xdbl[(size_t)(b * L_SEQ + t0 + r) * 128 + 64 + sl * 4];
    }
    float av[16];
#pragma unroll
    for (int sq = 0; sq < 4; sq++) {
        const float4 al = *(const float4*)&A_log[e * 16 + sq * 4];
#pragma unroll
        for (int j = 0; j < 4; j++)
            av[sq * 4 + j] = -fast_exp2(((const float*)&al)[j] * LOG2E);
    }
    float h[16];
#pragma unroll
    for (int s = 0; s < 16; s++) h[s] = 0.f;
    float sdt = 0.f;
    __syncthreads();

    const size_t rb = (size_t)(b * L_SEQ + t0) * 2048 + e;
    float dtv_n = __bfloat162float(dtb[rb]);
    float xv_n = __bfloat162float(xcb[rb]);
    for (int t = 0; t < LCH; t++) {
        const float dtv = dtv_n, xv = xv_n;
        if (t + 1 < LCH) {
            dtv_n = __bfloat162float(dtb[rb + (size_t)(t + 1) * 2048]);
            xv_n = __bfloat162float(xcb[rb + (size_t)(t + 1) * 2048]);
        }
        sdt += dtv;
        const float dtx = dtv * xv;
        const float dl2 = dtv * LOG2E;
#pragma unroll
        for (int sq = 0; sq < 4; sq++) {
            const float4 B4 = *(const float4*)&sB[t][sq * 4];
#pragma unroll
            for (int j = 0; j < 4; j++) {
                const int s = sq * 4 + j;
                const float Bv = ((const float*)&B4)[j];
                h[s] = fmaf(fast_exp2(dl2 * av[s]), h[s], Bv * dtx);
            }
        }
    }
    const size_t o = (((size_t)chunk * BATCH + b) * 2048 + e) * 16;
#pragma unroll
    for (int sq = 0; sq < 4; sq++) {
        ushort4 uh, up;
        uh.x = f2bu(h[sq * 4]);     uh.y = f2bu(h[sq * 4 + 1]);
        uh.z = f2bu(h[sq * 4 + 2]); uh.w = f2bu(h[sq * 4 + 3]);
        up.x = f2bu(fast_exp2(av[sq * 4] * sdt * LOG2E));
        up.y = f2bu(fast_exp2(av[sq * 4 + 1] * sdt * LOG2E));
        up.z = f2bu(fast_exp2(av[sq * 4 + 2] * sdt * LOG2E));
        up.w = f2bu(fast_exp2(av[sq * 4 + 3] * sdt * LOG2E));
        *(ushort4*)&hloc[o + sq * 4] = uh;
        *(ushort4*)&Pp[o + sq * 4] = up;
    }
}

__global__ __launch_bounds__(256) void scan_pass_b(
    const __hip_bfloat16* __restrict__ hloc, const __hip_bfloat16* __restrict__ Pp,
    __hip_bfloat16* __restrict__ h0)
{
    const int idx = blockIdx.x * 256 + threadIdx.x;   // 65536
    float h = 0.f;
    h0[idx] = __float2bfloat16(0.f);
    for (int c = 0; c < NCHUNK - 1; c++) {
        const float P = __bfloat162float(Pp[(size_t)c * 65536 + idx]);
        const float hl = __bfloat162float(hloc[(size_t)c * 65536 + idx]);
        h = fmaf(P, h, hl);
        h0[(size_t)(c + 1) * 65536 + idx] = __float2bfloat16(h);
    }
}

__global__ __launch_bounds__(256) void scan_pass_c(
    const __hip_bfloat16* __restrict__ dtb, const __hip_bfloat16* __restrict__ xcb,
    const float* __restrict__ xdbl, const __hip_bfloat16* __restrict__ zb,
    const float* __restrict__ A_log, const float* __restrict__ Dw,
    const __hip_bfloat16* __restrict__ h0, __hip_bfloat16* __restrict__ yb)
{
    __shared__ float sB[LCH][16];
    __shared__ float sC[LCH][16];
    const int tid = threadIdx.x;
    const int e = (blockIdx.x << 8) + tid;
    const int chunk = blockIdx.y;
    const int b = blockIdx.z;
    const int t0 = chunk * LCH;

    if (tid < LCH * 4) {
        const int r = tid >> 2, sl = tid & 3;
        *(float4*)&sB[r][sl * 4] =
            *(const float4*)&xdbl[(size_t)(b * L_SEQ + t0 + r) * 128 + 64 + sl * 4];
    } else if (tid < LCH * 8) {
        const int t2 = tid - LCH * 4;
        const int r = t2 >> 2, sl = t2 & 3;
        *(float4*)&sC[r][sl * 4] =
            *(const float4*)&xdbl[(size_t)(b * L_SEQ + t0 + r) * 128 + 80 + sl * 4];
    }
    float av[16];
#pragma unroll
    for (int sq = 0; sq < 4; sq++) {
        const float4 al = *(const float4*)&A_log[e * 16 + sq * 4];
#pragma unroll
        for (int j = 0; j < 4; j++)
            av[sq * 4 + j] = -fast_exp2(((const float*)&al)[j] * LOG2E);
    }
    const float De = Dw[e];
    float h[16];
    const size_t o = (((size_t)chunk * BATCH + b) * 2048 + e) * 16;
#pragma unroll
    for (int sq = 0; sq < 4; sq++) {
        const ushort4 hv = *(const ushort4*)&h0[o + sq * 4];
        h[sq * 4]     = bu2f(hv.x); h[sq * 4 + 1] = bu2f(hv.y);
        h[sq * 4 + 2] = bu2f(hv.z); h[sq * 4 + 3] = bu2f(hv.w);
    }
    __syncthreads();

    const size_t rb = (size_t)(b * L_SEQ + t0) * 2048 + e;
    float dtv_n = __bfloat162float(dtb[rb]);
    float xv_n = __bfloat162float(xcb[rb]);
    float zv_n = __bfloat162float(zb[rb]);
    for (int t = 0; t < LCH; t++) {
        const float dtv = dtv_n, xv = xv_n, zv = zv_n;
        if (t + 1 < LCH) {
            dtv_n = __bfloat162float(dtb[rb + (size_t)(t + 1) * 2048]);
            xv_n = __bfloat162float(xcb[rb + (size_t)(t + 1) * 2048]);
            zv_n = __bfloat162float(zb[rb + (size_t)(t + 1) * 2048]);
        }
        const float dtx = dtv * xv;
        const float dl2 = dtv * LOG2E;
        float yp0 = 0.f, yp1 = 0.f, yp2 = 0.f, yp3 = 0.f;
#pragma unroll
        for (int sq = 0; sq < 4; sq++) {
            const float4 B4 = *(const float4*)&sB[t][sq * 4];
            const float4 C4 = *(const float4*)&sC[t][sq * 4];
#pragma unroll
            for (int j = 0; j < 4; j++) {
                const int s = sq * 4 + j;
                const float Bv = ((const float*)&B4)[j];
                const float Cv = ((const float*)&C4)[j];
                h[s] = fmaf(fast_exp2(dl2 * av[s]), h[s], Bv * dtx);
                if (sq == 0) yp0 = fmaf(h[s], Cv, yp0);
                else if (sq == 1) yp1 = fmaf(h[s], Cv, yp1);
                else if (sq == 2) yp2 = fmaf(h[s], Cv, yp2);
                else yp3 = fmaf(h[s], Cv, yp3);
            }
        }
        float yv = (yp0 + yp1) + (yp2 + yp3);
        yv = fmaf(De, xv, yv);
        const float sig = 1.f / (1.f + __expf(-zv));
        yb[rb + (size_t)t * 2048] = __float2bfloat16(yv * zv * sig);
    }
}

extern "C" void kernel_launch(void* const* d_in, const int* in_sizes, int n_in,
                              void* d_out, int out_size, void* d_ws, size_t ws_size,
                              hipStream_t stream)
{
    const float* x_f    = (const float*)d_in[0];
    const float* x_h    = (const float*)d_in[1];
    const float* W_hf   = (const float*)d_in[2];
    const float* b_hf   = (const float*)d_in[3];
    const float* W_in   = (const float*)d_in[4];
    const float* conv_w = (const float*)d_in[5];
    const float* conv_b = (const float*)d_in[6];
    const float* W_x    = (const float*)d_in[7];
    const float* W_dt   = (const float*)d_in[8];
    const float* b_dt   = (const float*)d_in[9];
    const float* A_log  = (const float*)d_in[10];
    const float* Dw     = (const float*)d_in[11];
    const float* W_out  = (const float*)d_in[12];
    float* out = (float*)d_out;
    float* ws  = (float*)d_ws;

    // Workspace (f32 units; total 35,979,264 f = 143.9 MB, proven-safe).
    __hip_bfloat16* wout_b = (__hip_bfloat16*)(ws);              // 1,048,576 f
    __hip_bfloat16* win_b  = (__hip_bfloat16*)(ws + 1048576);    // 2,097,152 f
    __hip_bfloat16* xh_b   = (__hip_bfloat16*)(ws + 3145728);    // 2,097,152 f
    __hip_bfloat16* whf_b  = (__hip_bfloat16*)(ws + 5242880);    //   524,288 f
    __hip_bfloat16* m_b    = (__hip_bfloat16*)(ws + 5767168);    // 2,097,152 f
    __hip_bfloat16* hloc   = (__hip_bfloat16*)(ws + 1048576);    // scan overlay
    __hip_bfloat16* Pp     = (__hip_bfloat16*)(ws + 3145728);    // scan overlay
    __hip_bfloat16* h0     = (__hip_bfloat16*)(ws + 5242880);    // scan overlay
    __hip_bfloat16* wx_b   = (__hip_bfloat16*)(ws + 7864320);    //   131,072 f
    __hip_bfloat16* wdt_b  = (__hip_bfloat16*)(ws + 7995392);    //    65,536 f
    __hip_bfloat16* dtr_b  = (__hip_bfloat16*)(ws + 8060928);    //   131,072 f
    float*          xdbl   = ws + 10289152;                      //   524,288 f
    __hip_bfloat16* xin_b  = (__hip_bfloat16*)(ws + 10813440);   // 4,194,304 f
    __hip_bfloat16* z_b    = (__hip_bfloat16*)(ws + 15007744);   // 4,194,304 f
    __hip_bfloat16* xc_b   = (__hip_bfloat16*)(ws + 19202048);   // 4,194,304 f
    __hip_bfloat16* partb  = (__hip_bfloat16*)(ws + 23396352);   // G4 bf16 partials
    __hip_bfloat16* dt_b   = (__hip_bfloat16*)(ws + 27590656);   // 4,194,304 f
    __hip_bfloat16* part7b = (__hip_bfloat16*)(ws + 23396352);   // G7 overlay
    __hip_bfloat16* yb     = (__hip_bfloat16*)(ws + 31784960);   // 4,194,304 f

    // 0. pre-convert all static operands to bf16 (one fused launch)
    cvt_all<<<11648, 256, 0, stream>>>(
        W_out, W_in, x_h, W_hf, W_x, W_dt,
        wout_b, win_b, xh_b, whf_b, wx_b, wdt_b);

    // 1. m_b = bf16( x_f * sigmoid(x_h @ W_hf^T + b_hf) )  (SWAP XCD pin)
    mfma_gemm<1, true><<<dim3(32, 8, 1), 256, 0, stream>>>(
        xh_b, DMODEL, whf_b, DMODEL, DMODEL,
        nullptr, DMODEL, m_b, b_hf, x_f, DMODEL);

    // 2. [x_in | z] = m @ W_in^T  (256^2 tile + T2 swizzle + T4 depth-2)
    mfma_gemm256<2><<<dim3(16, 16, 1), 512, 0, stream>>>(
        m_b, DMODEL, win_b, DMODEL, DMODEL, xin_b, z_b);

    // 3. xc_b = bf16( silu(causal_conv4(x_in) + conv_b) )  4e/thread
    conv_silu_kernel<<<8192, 256, 0, stream>>>(
        xin_b, conv_w, conv_b, xc_b);

    // 4. x_dbl = xc @ W_x^T (padded N=128, split-K 8, bf16 partials) + reduce
    mfma_gemm<5, false><<<dim3(1, 32, 8), 256, 0, stream>>>(
        xc_b, DINNER, wx_b, DINNER, 256,
        nullptr, 128, partb, nullptr, nullptr, 0);
    reduce_xdbl<<<2048, 256, 0, stream>>>(partb, xdbl, dtr_b);

    // 5. dt_b = bf16( softplus(dt_r @ W_dt^T + b_dt) )
    mfma_gemm<3, false><<<dim3(16, 32, 1), 256, 0, stream>>>(
        dtr_b, 64, wdt_b, 64, 64,
        nullptr, 2048, dt_b, b_dt, nullptr, 0);

    // 6. chunked scan (lane-owns-channel, NCHUNK=64)
    scan_pass_a<<<dim3(8, NCHUNK - 1, BATCH), 256, 0, stream>>>(
        dt_b, xc_b, xdbl, A_log, hloc, Pp);
    scan_pass_b<<<256, 256, 0, stream>>>(hloc, Pp, h0);
    scan_pass_c<<<dim3(8, NCHUNK, BATCH), 256, 0, stream>>>(
        dt_b, xc_b, xdbl, z_b, A_log, Dw, h0, yb);

    // 7. out = y @ W_out^T on the 256^2 kernel (T4 depth-2), split-K=4;
    //    bf16 partials into part7b (dead partb+dt_b), then 4-slice reduce.
    mfma_gemm256<4><<<dim3(4, 16, 4), 512, 0, stream>>>(
        yb, DINNER, wout_b, DINNER, DINNER / 4, part7b, nullptr);
    reduce_out4<<<4096, 256, 0, stream>>>(part7b, out);
}